// Round 1
// baseline (439.756 us; speedup 1.0000x reference)
//
#include <hip/hip_runtime.h>

#define NEG_SLOPE 0.2f

__device__ __forceinline__ float lrelu(float z){ return z > 0.f ? z : NEG_SLOPE * z; }

__device__ __forceinline__ float wave_max64(float v){
  #pragma unroll
  for(int m = 32; m > 0; m >>= 1) v = fmaxf(v, __shfl_xor(v, m, 64));
  return v;
}
__device__ __forceinline__ float wave_sum64(float v){
  #pragma unroll
  for(int m = 32; m > 0; m >>= 1) v += __shfl_xor(v, m, 64);
  return v;
}

// ---------------- Layer-1 node scores: a_src1/a_dst1 [N,4] ----------------
// a_src1[n,h] = sum_c (x[n]·W1[:,h*64+c]) * att_src1[h,c] = x[n]·u_src[:,h]
__global__ __launch_bounds__(256) void k_node_scores1(
    const float* __restrict__ x, const float* __restrict__ W1,
    const float* __restrict__ att_src1, const float* __restrict__ att_dst1,
    float* __restrict__ a_src1, float* __restrict__ a_dst1, int N)
{
  __shared__ float us[3][4], ud[3][4];
  int t = threadIdx.x;
  if (t < 12) {
    int k = t >> 2, h = t & 3;
    float ss = 0.f, sd = 0.f;
    for (int c = 0; c < 64; ++c) {
      float w = W1[k * 256 + h * 64 + c];
      ss += w * att_src1[h * 64 + c];
      sd += w * att_dst1[h * 64 + c];
    }
    us[k][h] = ss; ud[k][h] = sd;
  }
  __syncthreads();
  int n = blockIdx.x * 256 + t;
  if (n < N) {
    float x0 = x[n * 3], x1 = x[n * 3 + 1], x2 = x[n * 3 + 2];
    float4 as, ad;
    as.x = x0 * us[0][0] + x1 * us[1][0] + x2 * us[2][0];
    as.y = x0 * us[0][1] + x1 * us[1][1] + x2 * us[2][1];
    as.z = x0 * us[0][2] + x1 * us[1][2] + x2 * us[2][2];
    as.w = x0 * us[0][3] + x1 * us[1][3] + x2 * us[2][3];
    ad.x = x0 * ud[0][0] + x1 * ud[1][0] + x2 * ud[2][0];
    ad.y = x0 * ud[0][1] + x1 * ud[1][1] + x2 * ud[2][1];
    ad.z = x0 * ud[0][2] + x1 * ud[1][2] + x2 * ud[2][2];
    ad.w = x0 * ud[0][3] + x1 * ud[1][3] + x2 * ud[2][3];
    ((float4*)a_src1)[n] = as;
    ((float4*)a_dst1)[n] = ad;
  }
}

// ---------------- CSR build ----------------
__global__ __launch_bounds__(256) void k_count(
    const int* __restrict__ ei, int E, int* __restrict__ cnt)
{
  int e = blockIdx.x * 256 + threadIdx.x;
  if (e < E) atomicAdd(&cnt[ei[E + e]], 1);
}

// inclusive scan of (cnt[i]+1) per 1024-chunk
__global__ __launch_bounds__(1024) void k_scan1(
    const int* __restrict__ cnt, int N, int* __restrict__ incl, int* __restrict__ csum)
{
  __shared__ int s[1024];
  int t = threadIdx.x;
  int i = blockIdx.x * 1024 + t;
  int v = (i < N) ? cnt[i] + 1 : 0;
  s[t] = v;
  __syncthreads();
  for (int off = 1; off < 1024; off <<= 1) {
    int u = (t >= off) ? s[t - off] : 0;
    __syncthreads();
    s[t] += u;
    __syncthreads();
  }
  if (i < N) incl[i] = s[t];
  if (t == 1023) csum[blockIdx.x] = s[1023];
}

__global__ __launch_bounds__(64) void k_scan2(
    const int* __restrict__ csum, int nch, int* __restrict__ cbase,
    int* __restrict__ offsets, int N)
{
  int t = threadIdx.x;
  int v = (t < nch) ? csum[t] : 0;
  int incl = v;
  #pragma unroll
  for (int m = 1; m < 64; m <<= 1) {
    int u = __shfl_up(incl, m, 64);
    if (t >= m) incl += u;
  }
  if (t < nch) cbase[t] = incl - v;   // exclusive base per chunk
  if (t == 63) offsets[N] = incl;     // grand total = E + N
}

__global__ __launch_bounds__(1024) void k_scan3(
    const int* __restrict__ cnt, const int* __restrict__ incl, const int* __restrict__ cbase,
    int N, int* __restrict__ offsets, int* __restrict__ cursor, int* __restrict__ srclist)
{
  int i = blockIdx.x * 1024 + threadIdx.x;
  if (i < N) {
    int c = cnt[i];
    int excl = incl[i] - (c + 1) + cbase[blockIdx.x];
    offsets[i] = excl;
    cursor[i] = excl;
    srclist[excl + c] = i;  // self-loop in last slot of segment
  }
}

__global__ __launch_bounds__(256) void k_fill(
    const int* __restrict__ ei, int E, int* __restrict__ cursor, int* __restrict__ srclist)
{
  int e = blockIdx.x * 256 + threadIdx.x;
  if (e < E) {
    int s = ei[e], d = ei[E + e];
    int pos = atomicAdd(&cursor[d], 1);
    srclist[pos] = s;
  }
}

// ---------------- Layer-1 aggregate + bias + ELU -> h1_act [N,256] ----------------
// one wave per node; aggregation factored through x (3 features):
// out[n,c] = W1[:,c] · (Σ_e α_e x[src_e]) ; α per head.
__global__ __launch_bounds__(256) void k_agg1(
    const float* __restrict__ x, const float* __restrict__ W1, const float* __restrict__ b1,
    const float* __restrict__ a_src1, const float* __restrict__ a_dst1,
    const int* __restrict__ offsets, const int* __restrict__ srclist,
    float* __restrict__ h1_act, int N)
{
  __shared__ float W1s[768];
  __shared__ float b1s[256];
  int t = threadIdx.x;
  for (int i = t; i < 768; i += 256) W1s[i] = W1[i];
  b1s[t] = b1[t];
  __syncthreads();

  int lane = t & 63;
  int n = blockIdx.x * 4 + (t >> 6);
  if (n >= N) return;

  int off = offsets[n];
  int deg = offsets[n + 1] - off;
  float4 adv = ((const float4*)a_dst1)[n];
  float ad[4] = {adv.x, adv.y, adv.z, adv.w};

  // pass 1: per-head max
  float m[4] = {-1e30f, -1e30f, -1e30f, -1e30f};
  for (int i = lane; i < deg; i += 64) {
    int s = srclist[off + i];
    float4 as = ((const float4*)a_src1)[s];
    m[0] = fmaxf(m[0], lrelu(as.x + ad[0]));
    m[1] = fmaxf(m[1], lrelu(as.y + ad[1]));
    m[2] = fmaxf(m[2], lrelu(as.z + ad[2]));
    m[3] = fmaxf(m[3], lrelu(as.w + ad[3]));
  }
  #pragma unroll
  for (int h = 0; h < 4; ++h) m[h] = wave_max64(m[h]);

  // pass 2: denom + weighted x accumulation (unnormalized)
  float den[4] = {0.f, 0.f, 0.f, 0.f};
  float xa[3][4];
  #pragma unroll
  for (int k = 0; k < 3; ++k)
    #pragma unroll
    for (int h = 0; h < 4; ++h) xa[k][h] = 0.f;

  for (int i = lane; i < deg; i += 64) {
    int s = srclist[off + i];
    float4 as = ((const float4*)a_src1)[s];
    float e0 = __expf(lrelu(as.x + ad[0]) - m[0]);
    float e1 = __expf(lrelu(as.y + ad[1]) - m[1]);
    float e2 = __expf(lrelu(as.z + ad[2]) - m[2]);
    float e3 = __expf(lrelu(as.w + ad[3]) - m[3]);
    den[0] += e0; den[1] += e1; den[2] += e2; den[3] += e3;
    float x0 = x[s * 3], x1 = x[s * 3 + 1], x2 = x[s * 3 + 2];
    xa[0][0] += e0 * x0; xa[0][1] += e1 * x0; xa[0][2] += e2 * x0; xa[0][3] += e3 * x0;
    xa[1][0] += e0 * x1; xa[1][1] += e1 * x1; xa[1][2] += e2 * x1; xa[1][3] += e3 * x1;
    xa[2][0] += e0 * x2; xa[2][1] += e1 * x2; xa[2][2] += e2 * x2; xa[2][3] += e3 * x2;
  }
  #pragma unroll
  for (int h = 0; h < 4; ++h) den[h] = wave_sum64(den[h]);
  #pragma unroll
  for (int k = 0; k < 3; ++k)
    #pragma unroll
    for (int h = 0; h < 4; ++h) xa[k][h] = wave_sum64(xa[k][h]);

  // epilogue: each lane owns 4 consecutive channels, head = lane>>4
  int hl = lane >> 4;
  int cb = lane * 4;
  float invd = 1.f / (den[hl] + 1e-16f);
  float X0 = xa[0][hl] * invd, X1 = xa[1][hl] * invd, X2 = xa[2][hl] * invd;
  float o[4];
  #pragma unroll
  for (int q = 0; q < 4; ++q) {
    float v = W1s[cb + q] * X0 + W1s[256 + cb + q] * X1 + W1s[512 + cb + q] * X2 + b1s[cb + q];
    o[q] = v > 0.f ? v : __expf(v) - 1.f;   // ELU
  }
  float4 ov = {o[0], o[1], o[2], o[3]};
  ((float4*)h1_act)[(size_t)n * 64 + lane] = ov;
}

// ---------------- Layer-2 projection: h2 = h1_act @ W2, + a_src2/a_dst2 ----------------
__global__ __launch_bounds__(128) void k_mm2(
    const float* __restrict__ h1_act, const float* __restrict__ W2,
    const float* __restrict__ att_src2, const float* __restrict__ att_dst2,
    float* __restrict__ h2, float* __restrict__ a_src2, float* __restrict__ a_dst2, int N)
{
  __shared__ float hs[16][256];
  __shared__ float red[2][2][16];
  int t = threadIdx.x;
  int n0 = blockIdx.x * 16;
  // stage 16 rows of h1_act
  for (int i = t; i < 1024; i += 128) {
    int r = i >> 6, c4 = i & 63;
    int n = n0 + r;
    float4 v = (n < N) ? ((const float4*)h1_act)[(size_t)n * 64 + c4] : make_float4(0.f, 0.f, 0.f, 0.f);
    ((float4*)&hs[r][0])[c4] = v;
  }
  __syncthreads();

  int c = t;  // channel 0..127
  float acc[16];
  #pragma unroll
  for (int j = 0; j < 16; ++j) acc[j] = 0.f;
  for (int k = 0; k < 256; k += 4) {
    float w0 = W2[(k + 0) * 128 + c];
    float w1 = W2[(k + 1) * 128 + c];
    float w2 = W2[(k + 2) * 128 + c];
    float w3 = W2[(k + 3) * 128 + c];
    #pragma unroll
    for (int j = 0; j < 16; ++j) {
      float4 h4 = *((const float4*)&hs[j][k]);
      acc[j] += h4.x * w0 + h4.y * w1 + h4.z * w2 + h4.w * w3;
    }
  }
  // store h2
  #pragma unroll
  for (int j = 0; j < 16; ++j) {
    int n = n0 + j;
    if (n < N) h2[(size_t)n * 128 + c] = acc[j];
  }
  // fused a_src2/a_dst2 = h2 · att (reduce over 128 threads = 2 waves)
  float asv = att_src2[c], adv = att_dst2[c];
  int lane = t & 63, w = t >> 6;
  #pragma unroll
  for (int j = 0; j < 16; ++j) {
    float ps = wave_sum64(acc[j] * asv);
    float pd = wave_sum64(acc[j] * adv);
    if (lane == 0) { red[w][0][j] = ps; red[w][1][j] = pd; }
  }
  __syncthreads();
  if (t < 16) {
    int n = n0 + t;
    if (n < N) {
      a_src2[n] = red[0][0][t] + red[1][0][t];
      a_dst2[n] = red[0][1][t] + red[1][1][t];
    }
  }
}

// ---------------- Layer-2 aggregate -> out [N,128] ----------------
__global__ __launch_bounds__(256) void k_agg2(
    const float* __restrict__ h2, const float* __restrict__ b2,
    const float* __restrict__ a_src2, const float* __restrict__ a_dst2,
    const int* __restrict__ offsets, const int* __restrict__ srclist,
    float* __restrict__ out, int N)
{
  int t = threadIdx.x, lane = t & 63;
  int n = blockIdx.x * 4 + (t >> 6);
  if (n >= N) return;
  int off = offsets[n];
  int deg = offsets[n + 1] - off;
  float adn = a_dst2[n];

  float m = -1e30f;
  for (int i = lane; i < deg; i += 64) {
    int s = srclist[off + i];
    m = fmaxf(m, lrelu(a_src2[s] + adn));
  }
  m = wave_max64(m);

  float den = 0.f;
  float2 acc = {0.f, 0.f};
  for (int j = 0; j < deg; ++j) {
    int s = srclist[off + j];
    float e = __expf(lrelu(a_src2[s] + adn) - m);
    den += e;
    float2 hv = ((const float2*)h2)[(size_t)s * 64 + lane];
    acc.x += e * hv.x;
    acc.y += e * hv.y;
  }
  float inv = 1.f / (den + 1e-16f);
  float2 bb = ((const float2*)b2)[lane];
  float2 o = {acc.x * inv + bb.x, acc.y * inv + bb.y};
  ((float2*)out)[(size_t)n * 64 + lane] = o;
}

extern "C" void kernel_launch(void* const* d_in, const int* in_sizes, int n_in,
                              void* d_out, int out_size, void* d_ws, size_t ws_size,
                              hipStream_t stream)
{
  const float* x        = (const float*)d_in[0];
  const int*   ei       = (const int*)d_in[1];
  const float* W1       = (const float*)d_in[2];
  const float* att_src1 = (const float*)d_in[3];
  const float* att_dst1 = (const float*)d_in[4];
  const float* b1       = (const float*)d_in[5];
  const float* W2       = (const float*)d_in[6];
  const float* att_src2 = (const float*)d_in[7];
  const float* att_dst2 = (const float*)d_in[8];
  const float* b2       = (const float*)d_in[9];
  float* out = (float*)d_out;

  int N = in_sizes[0] / 3;
  int E = in_sizes[1] / 2;

  char* p = (char*)d_ws;
  auto alloc = [&](size_t bytes) -> char* {
    char* r = p;
    p += (bytes + 255) & ~(size_t)255;
    return r;
  };
  float* a_src1  = (float*)alloc((size_t)4 * N * 4);
  float* a_dst1  = (float*)alloc((size_t)4 * N * 4);
  float* a_src2  = (float*)alloc((size_t)N * 4);
  float* a_dst2  = (float*)alloc((size_t)N * 4);
  int*   cnt     = (int*)alloc((size_t)N * 4);
  int*   incl    = (int*)alloc((size_t)N * 4);
  int*   csum    = (int*)alloc(64 * 4);
  int*   cbase   = (int*)alloc(64 * 4);
  int*   offsets = (int*)alloc((size_t)(N + 1) * 4);
  int*   cursor  = (int*)alloc((size_t)N * 4);
  int*   srclist = (int*)alloc((size_t)(E + N) * 4);
  float* h1_act  = (float*)alloc((size_t)256 * N * 4);
  float* h2      = (float*)alloc((size_t)128 * N * 4);

  int nch = (N + 1023) / 1024;

  hipMemsetAsync(cnt, 0, (size_t)N * 4, stream);
  k_node_scores1<<<(N + 255) / 256, 256, 0, stream>>>(x, W1, att_src1, att_dst1, a_src1, a_dst1, N);
  k_count<<<(E + 255) / 256, 256, 0, stream>>>(ei, E, cnt);
  k_scan1<<<nch, 1024, 0, stream>>>(cnt, N, incl, csum);
  k_scan2<<<1, 64, 0, stream>>>(csum, nch, cbase, offsets, N);
  k_scan3<<<nch, 1024, 0, stream>>>(cnt, incl, cbase, N, offsets, cursor, srclist);
  k_fill<<<(E + 255) / 256, 256, 0, stream>>>(ei, E, cursor, srclist);
  k_agg1<<<(N + 3) / 4, 256, 0, stream>>>(x, W1, b1, a_src1, a_dst1, offsets, srclist, h1_act, N);
  k_mm2<<<(N + 15) / 16, 128, 0, stream>>>(h1_act, W2, att_src2, att_dst2, h2, a_src2, a_dst2, N);
  k_agg2<<<(N + 3) / 4, 256, 0, stream>>>(h2, b2, a_src2, a_dst2, offsets, srclist, out, N);
}

// Round 2
// 357.928 us; speedup vs baseline: 1.2286x; 1.2286x over previous
//
#include <hip/hip_runtime.h>

#define NEG_SLOPE 0.2f

__device__ __forceinline__ float lrelu(float z){ return z > 0.f ? z : NEG_SLOPE * z; }

__device__ __forceinline__ float wave_max64(float v){
  #pragma unroll
  for(int m = 32; m > 0; m >>= 1) v = fmaxf(v, __shfl_xor(v, m, 64));
  return v;
}
__device__ __forceinline__ float wave_sum64(float v){
  #pragma unroll
  for(int m = 32; m > 0; m >>= 1) v += __shfl_xor(v, m, 64);
  return v;
}

// ---------------- Layer-1 node scores: a_src1/a_dst1 [N,4] ----------------
__global__ __launch_bounds__(256) void k_node_scores1(
    const float* __restrict__ x, const float* __restrict__ W1,
    const float* __restrict__ att_src1, const float* __restrict__ att_dst1,
    float* __restrict__ a_src1, float* __restrict__ a_dst1, int N)
{
  __shared__ float us[3][4], ud[3][4];
  int t = threadIdx.x;
  if (t < 12) {
    int k = t >> 2, h = t & 3;
    float ss = 0.f, sd = 0.f;
    for (int c = 0; c < 64; ++c) {
      float w = W1[k * 256 + h * 64 + c];
      ss += w * att_src1[h * 64 + c];
      sd += w * att_dst1[h * 64 + c];
    }
    us[k][h] = ss; ud[k][h] = sd;
  }
  __syncthreads();
  int n = blockIdx.x * 256 + t;
  if (n < N) {
    float x0 = x[n * 3], x1 = x[n * 3 + 1], x2 = x[n * 3 + 2];
    float4 as, ad;
    as.x = x0 * us[0][0] + x1 * us[1][0] + x2 * us[2][0];
    as.y = x0 * us[0][1] + x1 * us[1][1] + x2 * us[2][1];
    as.z = x0 * us[0][2] + x1 * us[1][2] + x2 * us[2][2];
    as.w = x0 * us[0][3] + x1 * us[1][3] + x2 * us[2][3];
    ad.x = x0 * ud[0][0] + x1 * ud[1][0] + x2 * ud[2][0];
    ad.y = x0 * ud[0][1] + x1 * ud[1][1] + x2 * ud[2][1];
    ad.z = x0 * ud[0][2] + x1 * ud[1][2] + x2 * ud[2][2];
    ad.w = x0 * ud[0][3] + x1 * ud[1][3] + x2 * ud[2][3];
    ((float4*)a_src1)[n] = as;
    ((float4*)a_dst1)[n] = ad;
  }
}

// ---------------- CSR build ----------------
__global__ __launch_bounds__(256) void k_count(
    const int* __restrict__ ei, int E, int* __restrict__ cnt)
{
  int e = blockIdx.x * 256 + threadIdx.x;
  if (e < E) atomicAdd(&cnt[ei[E + e]], 1);
}

__global__ __launch_bounds__(1024) void k_scan1(
    const int* __restrict__ cnt, int N, int* __restrict__ incl, int* __restrict__ csum)
{
  __shared__ int s[1024];
  int t = threadIdx.x;
  int i = blockIdx.x * 1024 + t;
  int v = (i < N) ? cnt[i] + 1 : 0;
  s[t] = v;
  __syncthreads();
  for (int off = 1; off < 1024; off <<= 1) {
    int u = (t >= off) ? s[t - off] : 0;
    __syncthreads();
    s[t] += u;
    __syncthreads();
  }
  if (i < N) incl[i] = s[t];
  if (t == 1023) csum[blockIdx.x] = s[1023];
}

__global__ __launch_bounds__(64) void k_scan2(
    const int* __restrict__ csum, int nch, int* __restrict__ cbase,
    int* __restrict__ offsets, int N)
{
  int t = threadIdx.x;
  int v = (t < nch) ? csum[t] : 0;
  int incl = v;
  #pragma unroll
  for (int m = 1; m < 64; m <<= 1) {
    int u = __shfl_up(incl, m, 64);
    if (t >= m) incl += u;
  }
  if (t < nch) cbase[t] = incl - v;
  if (t == 63) offsets[N] = incl;
}

__global__ __launch_bounds__(1024) void k_scan3(
    const int* __restrict__ cnt, const int* __restrict__ incl, const int* __restrict__ cbase,
    int N, int* __restrict__ offsets, int* __restrict__ cursor, int* __restrict__ srclist)
{
  int i = blockIdx.x * 1024 + threadIdx.x;
  if (i < N) {
    int c = cnt[i];
    int excl = incl[i] - (c + 1) + cbase[blockIdx.x];
    offsets[i] = excl;
    cursor[i] = excl;
    srclist[excl + c] = i;  // self-loop in last slot
  }
}

__global__ __launch_bounds__(256) void k_fill(
    const int* __restrict__ ei, int E, int* __restrict__ cursor, int* __restrict__ srclist)
{
  int e = blockIdx.x * 256 + threadIdx.x;
  if (e < E) {
    int s = ei[e], d = ei[E + e];
    int pos = atomicAdd(&cursor[d], 1);
    srclist[pos] = s;
  }
}

// ---------------- Layer-1 aggregate -> X[N,16] = {den[4], xa[3][4]} ----------------
// 32-lane groups, 2 nodes per wave, 8 nodes per block.
__global__ __launch_bounds__(256) void k_agg1(
    const float* __restrict__ x,
    const float* __restrict__ a_src1, const float* __restrict__ a_dst1,
    const int* __restrict__ offsets, const int* __restrict__ srclist,
    float* __restrict__ X, int N)
{
  int t = threadIdx.x;
  int lane = t & 63;
  int g = lane >> 5;          // group within wave
  int r = lane & 31;          // lane within group
  int n = blockIdx.x * 8 + (t >> 6) * 2 + g;
  if (n >= N) return;

  int off = offsets[n];
  int deg = offsets[n + 1] - off;
  float4 ad = ((const float4*)a_dst1)[n];

  int c0 = min(deg, 32);
  int s0 = 0;
  float a0 = -1e30f, a1 = -1e30f, a2 = -1e30f, a3 = -1e30f;
  float x0 = 0.f, x1 = 0.f, x2 = 0.f;
  if (r < c0) {
    s0 = srclist[off + r];
    float4 as = ((const float4*)a_src1)[s0];
    a0 = lrelu(as.x + ad.x); a1 = lrelu(as.y + ad.y);
    a2 = lrelu(as.z + ad.z); a3 = lrelu(as.w + ad.w);
    x0 = x[s0 * 3]; x1 = x[s0 * 3 + 1]; x2 = x[s0 * 3 + 2];
  }
  float m0 = a0, m1 = a1, m2 = a2, m3 = a3;
  for (int base = 32; base < deg; base += 32) {   // rare (deg>32)
    if (r < deg - base) {
      int s = srclist[off + base + r];
      float4 as = ((const float4*)a_src1)[s];
      m0 = fmaxf(m0, lrelu(as.x + ad.x)); m1 = fmaxf(m1, lrelu(as.y + ad.y));
      m2 = fmaxf(m2, lrelu(as.z + ad.z)); m3 = fmaxf(m3, lrelu(as.w + ad.w));
    }
  }
  #pragma unroll
  for (int msk = 16; msk > 0; msk >>= 1) {
    m0 = fmaxf(m0, __shfl_xor(m0, msk, 32)); m1 = fmaxf(m1, __shfl_xor(m1, msk, 32));
    m2 = fmaxf(m2, __shfl_xor(m2, msk, 32)); m3 = fmaxf(m3, __shfl_xor(m3, msk, 32));
  }

  float e0 = (r < c0) ? __expf(a0 - m0) : 0.f;
  float e1 = (r < c0) ? __expf(a1 - m1) : 0.f;
  float e2 = (r < c0) ? __expf(a2 - m2) : 0.f;
  float e3 = (r < c0) ? __expf(a3 - m3) : 0.f;
  float d0 = e0, d1 = e1, d2 = e2, d3 = e3;
  float xa00 = e0 * x0, xa01 = e1 * x0, xa02 = e2 * x0, xa03 = e3 * x0;
  float xa10 = e0 * x1, xa11 = e1 * x1, xa12 = e2 * x1, xa13 = e3 * x1;
  float xa20 = e0 * x2, xa21 = e1 * x2, xa22 = e2 * x2, xa23 = e3 * x2;

  for (int base = 32; base < deg; base += 32) {   // rare
    if (r < deg - base) {
      int s = srclist[off + base + r];
      float4 as = ((const float4*)a_src1)[s];
      float ee0 = __expf(lrelu(as.x + ad.x) - m0);
      float ee1 = __expf(lrelu(as.y + ad.y) - m1);
      float ee2 = __expf(lrelu(as.z + ad.z) - m2);
      float ee3 = __expf(lrelu(as.w + ad.w) - m3);
      float xx0 = x[s * 3], xx1 = x[s * 3 + 1], xx2 = x[s * 3 + 2];
      d0 += ee0; d1 += ee1; d2 += ee2; d3 += ee3;
      xa00 += ee0 * xx0; xa01 += ee1 * xx0; xa02 += ee2 * xx0; xa03 += ee3 * xx0;
      xa10 += ee0 * xx1; xa11 += ee1 * xx1; xa12 += ee2 * xx1; xa13 += ee3 * xx1;
      xa20 += ee0 * xx2; xa21 += ee1 * xx2; xa22 += ee2 * xx2; xa23 += ee3 * xx2;
    }
  }

  #pragma unroll
  for (int msk = 16; msk > 0; msk >>= 1) {
    d0 += __shfl_xor(d0, msk, 32); d1 += __shfl_xor(d1, msk, 32);
    d2 += __shfl_xor(d2, msk, 32); d3 += __shfl_xor(d3, msk, 32);
    xa00 += __shfl_xor(xa00, msk, 32); xa01 += __shfl_xor(xa01, msk, 32);
    xa02 += __shfl_xor(xa02, msk, 32); xa03 += __shfl_xor(xa03, msk, 32);
    xa10 += __shfl_xor(xa10, msk, 32); xa11 += __shfl_xor(xa11, msk, 32);
    xa12 += __shfl_xor(xa12, msk, 32); xa13 += __shfl_xor(xa13, msk, 32);
    xa20 += __shfl_xor(xa20, msk, 32); xa21 += __shfl_xor(xa21, msk, 32);
    xa22 += __shfl_xor(xa22, msk, 32); xa23 += __shfl_xor(xa23, msk, 32);
  }

  if (r < 16) {
    int j = r;
    float v =
      j == 0 ? d0 : j == 1 ? d1 : j == 2 ? d2 : j == 3 ? d3 :
      j == 4 ? xa00 : j == 5 ? xa01 : j == 6 ? xa02 : j == 7 ? xa03 :
      j == 8 ? xa10 : j == 9 ? xa11 : j == 10 ? xa12 : j == 11 ? xa13 :
      j == 12 ? xa20 : j == 13 ? xa21 : j == 14 ? xa22 : xa23;
    X[(size_t)n * 16 + j] = v;
  }
}

// ---------------- Fused expand + GEMM + layer-2 scores ----------------
// h1[n,ch] = ELU(W1[:,ch]·X̂_h(n) + b1[ch]);  h2 = h1 @ W2;  a_*2 = h2·att_*2
__global__ __launch_bounds__(256) void k_mm2(
    const float* __restrict__ Xc, const float* __restrict__ W1, const float* __restrict__ b1,
    const float* __restrict__ W2, const float* __restrict__ att_src2, const float* __restrict__ att_dst2,
    float* __restrict__ h2, float* __restrict__ a_src2, float* __restrict__ a_dst2, int N)
{
  __shared__ float W1s[768];
  __shared__ float b1s[256];
  __shared__ float Xs[32 * 16];
  __shared__ float h1s[32][256];
  int t = threadIdx.x;
  int n0 = blockIdx.x * 32;

  for (int i = t; i < 768; i += 256) W1s[i] = W1[i];
  b1s[t] = b1[t];
  for (int i = t; i < 512; i += 256) {
    int idx = n0 * 16 + i;
    Xs[i] = (idx < N * 16) ? Xc[idx] : 0.f;
  }
  __syncthreads();

  // expansion: thread owns channel t for all 32 nodes; h = t>>6 is wave-uniform
  {
    int h = t >> 6;
    float w0 = W1s[t], w1 = W1s[256 + t], w2 = W1s[512 + t], bb = b1s[t];
    for (int i = 0; i < 32; ++i) {
      float den = Xs[i * 16 + h];
      float inv = 1.f / (den + 1e-16f);
      float X0 = Xs[i * 16 + 4 + h] * inv;
      float X1 = Xs[i * 16 + 8 + h] * inv;
      float X2 = Xs[i * 16 + 12 + h] * inv;
      float v = w0 * X0 + w1 * X1 + w2 * X2 + bb;
      h1s[i][t] = v > 0.f ? v : __expf(v) - 1.f;
    }
  }
  __syncthreads();

  // GEMM: thread (nr = t>>5, nc = t&31) owns nodes nr*4..+3, channels nc*4..+3
  int nc = t & 31, nr = t >> 5;
  int rb = nr * 4;
  float acc[4][4];
  #pragma unroll
  for (int i = 0; i < 4; ++i)
    #pragma unroll
    for (int j = 0; j < 4; ++j) acc[i][j] = 0.f;

  const float* W2p = W2 + nc * 4;
  for (int k = 0; k < 256; k += 4) {
    float4 B0 = *(const float4*)(W2p + (size_t)(k + 0) * 128);
    float4 B1 = *(const float4*)(W2p + (size_t)(k + 1) * 128);
    float4 B2 = *(const float4*)(W2p + (size_t)(k + 2) * 128);
    float4 B3 = *(const float4*)(W2p + (size_t)(k + 3) * 128);
    #pragma unroll
    for (int i = 0; i < 4; ++i) {
      float4 A = *(const float4*)&h1s[rb + i][k];
      acc[i][0] += A.x * B0.x + A.y * B1.x + A.z * B2.x + A.w * B3.x;
      acc[i][1] += A.x * B0.y + A.y * B1.y + A.z * B2.y + A.w * B3.y;
      acc[i][2] += A.x * B0.z + A.y * B1.z + A.z * B2.z + A.w * B3.z;
      acc[i][3] += A.x * B0.w + A.y * B1.w + A.z * B2.w + A.w * B3.w;
    }
  }

  float4 asv = *(const float4*)(att_src2 + nc * 4);
  float4 adv = *(const float4*)(att_dst2 + nc * 4);
  #pragma unroll
  for (int i = 0; i < 4; ++i) {
    int n = n0 + rb + i;
    float4 o = {acc[i][0], acc[i][1], acc[i][2], acc[i][3]};
    if (n < N) *((float4*)(h2 + (size_t)n * 128 + nc * 4)) = o;
    float ps = o.x * asv.x + o.y * asv.y + o.z * asv.z + o.w * asv.w;
    float pd = o.x * adv.x + o.y * adv.y + o.z * adv.z + o.w * adv.w;
    #pragma unroll
    for (int msk = 16; msk > 0; msk >>= 1) {
      ps += __shfl_xor(ps, msk, 32);
      pd += __shfl_xor(pd, msk, 32);
    }
    if (nc == 0 && n < N) { a_src2[n] = ps; a_dst2[n] = pd; }
  }
}

// ---------------- Layer-2 aggregate -> out [N,128] ----------------
// wave per node; per-edge e precomputed vector-wise, inner loop fully pipelined
__global__ __launch_bounds__(256) void k_agg2(
    const float* __restrict__ h2, const float* __restrict__ b2,
    const float* __restrict__ a_src2, const float* __restrict__ a_dst2,
    const int* __restrict__ offsets, const int* __restrict__ srclist,
    float* __restrict__ out, int N)
{
  int t = threadIdx.x, lane = t & 63;
  int n = blockIdx.x * 4 + (t >> 6);
  if (n >= N) return;
  int off = offsets[n];
  int deg = offsets[n + 1] - off;
  float adn = a_dst2[n];

  int c0 = min(deg, 64);
  int s_l = 0;
  float a_l = -1e30f;
  if (lane < c0) {
    s_l = srclist[off + lane];
    a_l = lrelu(a_src2[s_l] + adn);
  }
  float m = a_l;
  for (int base = 64; base < deg; base += 64) {   // rare
    if (lane < deg - base)
      m = fmaxf(m, lrelu(a_src2[srclist[off + base + lane]] + adn));
  }
  m = wave_max64(m);

  float e_l = (lane < c0) ? __expf(a_l - m) : 0.f;
  float denp = e_l;
  float2 acc = {0.f, 0.f};
  for (int j = 0; j < c0; ++j) {
    int s = __shfl(s_l, j);
    float e = __shfl(e_l, j);
    float2 hv = ((const float2*)h2)[(size_t)s * 64 + lane];
    acc.x += e * hv.x;
    acc.y += e * hv.y;
  }
  for (int base = 64; base < deg; base += 64) {   // rare
    int rem = min(64, deg - base);
    int sl2 = 0; float el2 = 0.f;
    if (lane < rem) {
      sl2 = srclist[off + base + lane];
      el2 = __expf(lrelu(a_src2[sl2] + adn) - m);
    }
    denp += el2;
    for (int j = 0; j < rem; ++j) {
      int s = __shfl(sl2, j);
      float e = __shfl(el2, j);
      float2 hv = ((const float2*)h2)[(size_t)s * 64 + lane];
      acc.x += e * hv.x;
      acc.y += e * hv.y;
    }
  }
  float den = wave_sum64(denp);
  float inv = 1.f / (den + 1e-16f);
  float2 bb = ((const float2*)b2)[lane];
  float2 o = {acc.x * inv + bb.x, acc.y * inv + bb.y};
  ((float2*)out)[(size_t)n * 64 + lane] = o;
}

extern "C" void kernel_launch(void* const* d_in, const int* in_sizes, int n_in,
                              void* d_out, int out_size, void* d_ws, size_t ws_size,
                              hipStream_t stream)
{
  const float* x        = (const float*)d_in[0];
  const int*   ei       = (const int*)d_in[1];
  const float* W1       = (const float*)d_in[2];
  const float* att_src1 = (const float*)d_in[3];
  const float* att_dst1 = (const float*)d_in[4];
  const float* b1       = (const float*)d_in[5];
  const float* W2       = (const float*)d_in[6];
  const float* att_src2 = (const float*)d_in[7];
  const float* att_dst2 = (const float*)d_in[8];
  const float* b2       = (const float*)d_in[9];
  float* out = (float*)d_out;

  int N = in_sizes[0] / 3;
  int E = in_sizes[1] / 2;

  char* p = (char*)d_ws;
  auto alloc = [&](size_t bytes) -> char* {
    char* r = p;
    p += (bytes + 255) & ~(size_t)255;
    return r;
  };
  float* a_src1  = (float*)alloc((size_t)4 * N * 4);
  float* a_dst1  = (float*)alloc((size_t)4 * N * 4);
  float* a_src2  = (float*)alloc((size_t)N * 4);
  float* a_dst2  = (float*)alloc((size_t)N * 4);
  int*   cnt     = (int*)alloc((size_t)N * 4);
  int*   incl    = (int*)alloc((size_t)N * 4);
  int*   csum    = (int*)alloc(64 * 4);
  int*   cbase   = (int*)alloc(64 * 4);
  int*   offsets = (int*)alloc((size_t)(N + 1) * 4);
  int*   cursor  = (int*)alloc((size_t)N * 4);
  int*   srclist = (int*)alloc((size_t)(E + N) * 4);
  float* Xc      = (float*)alloc((size_t)16 * N * 4);
  float* h2      = (float*)alloc((size_t)128 * N * 4);

  int nch = (N + 1023) / 1024;

  hipMemsetAsync(cnt, 0, (size_t)N * 4, stream);
  k_node_scores1<<<(N + 255) / 256, 256, 0, stream>>>(x, W1, att_src1, att_dst1, a_src1, a_dst1, N);
  k_count<<<(E + 255) / 256, 256, 0, stream>>>(ei, E, cnt);
  k_scan1<<<nch, 1024, 0, stream>>>(cnt, N, incl, csum);
  k_scan2<<<1, 64, 0, stream>>>(csum, nch, cbase, offsets, N);
  k_scan3<<<nch, 1024, 0, stream>>>(cnt, incl, cbase, N, offsets, cursor, srclist);
  k_fill<<<(E + 255) / 256, 256, 0, stream>>>(ei, E, cursor, srclist);
  k_agg1<<<(N + 7) / 8, 256, 0, stream>>>(x, a_src1, a_dst1, offsets, srclist, Xc, N);
  k_mm2<<<(N + 31) / 32, 256, 0, stream>>>(Xc, W1, b1, W2, att_src2, att_dst2, h2, a_src2, a_dst2, N);
  k_agg2<<<(N + 3) / 4, 256, 0, stream>>>(h2, b2, a_src2, a_dst2, offsets, srclist, out, N);
}

// Round 7
// 293.036 us; speedup vs baseline: 1.5007x; 1.2214x over previous
//
#include <hip/hip_runtime.h>

#define NEG_SLOPE 0.2f
typedef unsigned short ushort_t;
typedef __attribute__((ext_vector_type(8))) short bf16x8;
typedef __attribute__((ext_vector_type(4))) float f32x4;

__device__ __forceinline__ float lrelu(float z){ return z > 0.f ? z : NEG_SLOPE * z; }

__device__ __forceinline__ ushort_t bf16_rn(float x){
  union { float f; unsigned u; } v; v.f = x;
  unsigned r = v.u + 0x7FFF + ((v.u >> 16) & 1);
  return (ushort_t)(r >> 16);
}
__device__ __forceinline__ float bf16_to_f(ushort_t h){
  union { unsigned u; float f; } v; v.u = ((unsigned)h) << 16;
  return v.f;
}

// ---------------- prep: pack W2 into bf16 hi/lo MFMA-fragment layout + u-vectors ----------------
// w2pk index ((kc*4+g)*128 + n)*8 + e  holds W2[kc*32 + g*8 + e][n]
__global__ __launch_bounds__(256) void k_prep(
    const float* __restrict__ W1, const float* __restrict__ att_src1, const float* __restrict__ att_dst1,
    const float* __restrict__ W2, ushort_t* __restrict__ w2hi, ushort_t* __restrict__ w2lo,
    float* __restrict__ uv)
{
  int gid = blockIdx.x * 256 + threadIdx.x;
  if (gid < 4096) {
    int kc = gid >> 9, g = (gid >> 7) & 3, n = gid & 127;
    #pragma unroll
    for (int e = 0; e < 8; ++e) {
      int k = kc * 32 + g * 8 + e;
      float w = W2[k * 128 + n];
      ushort_t hi = bf16_rn(w);
      ushort_t lo = bf16_rn(w - bf16_to_f(hi));
      w2hi[(size_t)gid * 8 + e] = hi;
      w2lo[(size_t)gid * 8 + e] = lo;
    }
  } else if (gid < 4120) {
    int j = gid - 4096;              // 0..23 ; uv[k*4+h] = us, uv[12+k*4+h] = ud
    int jj = j % 12;
    int k = jj >> 2, h = jj & 3;
    const float* att = (j < 12) ? att_src1 : att_dst1;
    float s = 0.f;
    for (int c = 0; c < 64; ++c) s += W1[k * 256 + h * 64 + c] * att[h * 64 + c];
    uv[j] = s;
  }
}

// ---------------- CSR build ----------------
__global__ __launch_bounds__(256) void k_count(
    const int* __restrict__ ei, int E, int* __restrict__ cnt)
{
  int e = blockIdx.x * 256 + threadIdx.x;
  if (e < E) atomicAdd(&cnt[ei[E + e]], 1);
}

__global__ __launch_bounds__(1024) void k_scan1(
    const int* __restrict__ cnt, int N, int* __restrict__ incl, int* __restrict__ csum)
{
  __shared__ int s[1024];
  int t = threadIdx.x;
  int i = blockIdx.x * 1024 + t;
  int v = (i < N) ? cnt[i] + 1 : 0;
  s[t] = v;
  __syncthreads();
  for (int off = 1; off < 1024; off <<= 1) {
    int u = (t >= off) ? s[t - off] : 0;
    __syncthreads();
    s[t] += u;
    __syncthreads();
  }
  if (i < N) incl[i] = s[t];
  if (t == 1023) csum[blockIdx.x] = s[1023];
}

__global__ __launch_bounds__(64) void k_scan2(
    const int* __restrict__ csum, int nch, int* __restrict__ cbase,
    int* __restrict__ offsets, int N)
{
  int t = threadIdx.x;
  int v = (t < nch) ? csum[t] : 0;
  int incl = v;
  #pragma unroll
  for (int m = 1; m < 64; m <<= 1) {
    int u = __shfl_up(incl, m, 64);
    if (t >= m) incl += u;
  }
  if (t < nch) cbase[t] = incl - v;
  if (t == 63) offsets[N] = incl;
}

__global__ __launch_bounds__(1024) void k_scan3(
    const int* __restrict__ cnt, const int* __restrict__ incl, const int* __restrict__ cbase,
    int N, int* __restrict__ offsets, int* __restrict__ cursor, int* __restrict__ srclist)
{
  int i = blockIdx.x * 1024 + threadIdx.x;
  if (i < N) {
    int c = cnt[i];
    int excl = incl[i] - (c + 1) + cbase[blockIdx.x];
    offsets[i] = excl;
    cursor[i] = excl;
    srclist[excl + c] = i;  // self-loop in last slot
  }
}

__global__ __launch_bounds__(256) void k_fill(
    const int* __restrict__ ei, int E, int* __restrict__ cursor, int* __restrict__ srclist)
{
  int e = blockIdx.x * 256 + threadIdx.x;
  if (e < E) {
    int s = ei[e], d = ei[E + e];
    int pos = atomicAdd(&cursor[d], 1);
    srclist[pos] = s;
  }
}

// ---------------- Layer-1 aggregate -> X[N,16] = {den[4], xa0[4], xa1[4], xa2[4]} ----------------
// 32-lane group per node; edge scores recomputed from x via u-vectors (no a_src1 array).
__global__ __launch_bounds__(256) void k_agg1(
    const float* __restrict__ x, const float* __restrict__ uv,
    const int* __restrict__ offsets, const int* __restrict__ srclist,
    float* __restrict__ X, int N)
{
  int t = threadIdx.x;
  int lane = t & 63;
  int g = lane >> 5, r = lane & 31;
  int n = blockIdx.x * 8 + (t >> 6) * 2 + g;
  if (n >= N) return;

  float us[12], ud[12];
  #pragma unroll
  for (int j = 0; j < 12; ++j) { us[j] = uv[j]; ud[j] = uv[12 + j]; }

  float xn0 = x[n * 3], xn1 = x[n * 3 + 1], xn2 = x[n * 3 + 2];
  float ad0 = xn0 * ud[0] + xn1 * ud[4] + xn2 * ud[8];
  float ad1 = xn0 * ud[1] + xn1 * ud[5] + xn2 * ud[9];
  float ad2 = xn0 * ud[2] + xn1 * ud[6] + xn2 * ud[10];
  float ad3 = xn0 * ud[3] + xn1 * ud[7] + xn2 * ud[11];

  int off = offsets[n];
  int deg = offsets[n + 1] - off;
  int c0 = min(deg, 32);
  float a0 = -1e30f, a1 = -1e30f, a2 = -1e30f, a3 = -1e30f;
  float x0 = 0.f, x1 = 0.f, x2 = 0.f;
  if (r < c0) {
    int s = srclist[off + r];
    x0 = x[s * 3]; x1 = x[s * 3 + 1]; x2 = x[s * 3 + 2];
    a0 = lrelu(x0 * us[0] + x1 * us[4] + x2 * us[8]  + ad0);
    a1 = lrelu(x0 * us[1] + x1 * us[5] + x2 * us[9]  + ad1);
    a2 = lrelu(x0 * us[2] + x1 * us[6] + x2 * us[10] + ad2);
    a3 = lrelu(x0 * us[3] + x1 * us[7] + x2 * us[11] + ad3);
  }
  float m0 = a0, m1 = a1, m2 = a2, m3 = a3;
  for (int base = 32; base < deg; base += 32) {   // rare: deg>32
    if (r < deg - base) {
      int s = srclist[off + base + r];
      float y0 = x[s * 3], y1 = x[s * 3 + 1], y2 = x[s * 3 + 2];
      m0 = fmaxf(m0, lrelu(y0 * us[0] + y1 * us[4] + y2 * us[8]  + ad0));
      m1 = fmaxf(m1, lrelu(y0 * us[1] + y1 * us[5] + y2 * us[9]  + ad1));
      m2 = fmaxf(m2, lrelu(y0 * us[2] + y1 * us[6] + y2 * us[10] + ad2));
      m3 = fmaxf(m3, lrelu(y0 * us[3] + y1 * us[7] + y2 * us[11] + ad3));
    }
  }
  #pragma unroll
  for (int msk = 16; msk > 0; msk >>= 1) {
    m0 = fmaxf(m0, __shfl_xor(m0, msk, 32)); m1 = fmaxf(m1, __shfl_xor(m1, msk, 32));
    m2 = fmaxf(m2, __shfl_xor(m2, msk, 32)); m3 = fmaxf(m3, __shfl_xor(m3, msk, 32));
  }

  float e0 = (r < c0) ? __expf(a0 - m0) : 0.f;
  float e1 = (r < c0) ? __expf(a1 - m1) : 0.f;
  float e2 = (r < c0) ? __expf(a2 - m2) : 0.f;
  float e3 = (r < c0) ? __expf(a3 - m3) : 0.f;
  float d0 = e0, d1 = e1, d2 = e2, d3 = e3;
  float xa00 = e0 * x0, xa01 = e1 * x0, xa02 = e2 * x0, xa03 = e3 * x0;
  float xa10 = e0 * x1, xa11 = e1 * x1, xa12 = e2 * x1, xa13 = e3 * x1;
  float xa20 = e0 * x2, xa21 = e1 * x2, xa22 = e2 * x2, xa23 = e3 * x2;

  for (int base = 32; base < deg; base += 32) {   // rare
    if (r < deg - base) {
      int s = srclist[off + base + r];
      float y0 = x[s * 3], y1 = x[s * 3 + 1], y2 = x[s * 3 + 2];
      float ee0 = __expf(lrelu(y0 * us[0] + y1 * us[4] + y2 * us[8]  + ad0) - m0);
      float ee1 = __expf(lrelu(y0 * us[1] + y1 * us[5] + y2 * us[9]  + ad1) - m1);
      float ee2 = __expf(lrelu(y0 * us[2] + y1 * us[6] + y2 * us[10] + ad2) - m2);
      float ee3 = __expf(lrelu(y0 * us[3] + y1 * us[7] + y2 * us[11] + ad3) - m3);
      d0 += ee0; d1 += ee1; d2 += ee2; d3 += ee3;
      xa00 += ee0 * y0; xa01 += ee1 * y0; xa02 += ee2 * y0; xa03 += ee3 * y0;
      xa10 += ee0 * y1; xa11 += ee1 * y1; xa12 += ee2 * y1; xa13 += ee3 * y1;
      xa20 += ee0 * y2; xa21 += ee1 * y2; xa22 += ee2 * y2; xa23 += ee3 * y2;
    }
  }

  #pragma unroll
  for (int msk = 16; msk > 0; msk >>= 1) {
    d0 += __shfl_xor(d0, msk, 32); d1 += __shfl_xor(d1, msk, 32);
    d2 += __shfl_xor(d2, msk, 32); d3 += __shfl_xor(d3, msk, 32);
    xa00 += __shfl_xor(xa00, msk, 32); xa01 += __shfl_xor(xa01, msk, 32);
    xa02 += __shfl_xor(xa02, msk, 32); xa03 += __shfl_xor(xa03, msk, 32);
    xa10 += __shfl_xor(xa10, msk, 32); xa11 += __shfl_xor(xa11, msk, 32);
    xa12 += __shfl_xor(xa12, msk, 32); xa13 += __shfl_xor(xa13, msk, 32);
    xa20 += __shfl_xor(xa20, msk, 32); xa21 += __shfl_xor(xa21, msk, 32);
    xa22 += __shfl_xor(xa22, msk, 32); xa23 += __shfl_xor(xa23, msk, 32);
  }

  if (r < 16) {
    int j = r;
    float v =
      j == 0 ? d0 : j == 1 ? d1 : j == 2 ? d2 : j == 3 ? d3 :
      j == 4 ? xa00 : j == 5 ? xa01 : j == 6 ? xa02 : j == 7 ? xa03 :
      j == 8 ? xa10 : j == 9 ? xa11 : j == 10 ? xa12 : j == 11 ? xa13 :
      j == 12 ? xa20 : j == 13 ? xa21 : j == 14 ? xa22 : xa23;
    X[(size_t)n * 16 + j] = v;
  }
}

// ---------------- Fused expand + split-bf16 MFMA GEMM + layer-2 scores ----------------
// Block: 32 nodes, 256 threads (4 waves). Wave w owns channels [w*32, w*32+32).
// h1 = ELU(W1·X̂ + b1) -> bf16 hi/lo in XOR-swizzled LDS -> 3-term MFMA vs packed W2.
__global__ __launch_bounds__(256) void k_mm2(
    const float* __restrict__ Xc, const float* __restrict__ W1, const float* __restrict__ b1,
    const ushort_t* __restrict__ w2hi, const ushort_t* __restrict__ w2lo,
    const float* __restrict__ att_src2, const float* __restrict__ att_dst2,
    float* __restrict__ h2, float* __restrict__ a_src2, float* __restrict__ a_dst2, int N)
{
  __shared__ ushort_t h1hi[32 * 256];
  __shared__ ushort_t h1lo[32 * 256];
  __shared__ float Xs[512];
  __shared__ float W1s[768];
  __shared__ float b1s[256];
  __shared__ float invs[128];
  __shared__ float sred_s[32][4];
  __shared__ float sred_d[32][4];

  int t = threadIdx.x;
  int n0 = blockIdx.x * 32;

  for (int i = t; i < 768; i += 256) W1s[i] = W1[i];
  b1s[t] = b1[t];
  for (int i = t; i < 512; i += 256) {
    int idx = n0 * 16 + i;
    Xs[i] = (idx < N * 16) ? Xc[idx] : 0.f;
  }
  __syncthreads();
  if (t < 128) invs[t] = 1.f / (Xs[(t >> 2) * 16 + (t & 3)] + 1e-16f);
  __syncthreads();

  // expansion: thread t owns channel c=t for all 32 nodes
  {
    int c = t, h = t >> 6;
    float w0 = W1s[c], w1 = W1s[256 + c], w2v = W1s[512 + c], bb = b1s[c];
    #pragma unroll 4
    for (int i = 0; i < 32; ++i) {
      float inv = invs[i * 4 + h];
      float X0 = Xs[i * 16 + 4 + h] * inv;
      float X1 = Xs[i * 16 + 8 + h] * inv;
      float X2 = Xs[i * 16 + 12 + h] * inv;
      float v = fmaf(w0, X0, fmaf(w1, X1, fmaf(w2v, X2, bb)));
      v = v > 0.f ? v : __expf(v) - 1.f;      // ELU
      ushort_t hi = bf16_rn(v);
      ushort_t lo = bf16_rn(v - bf16_to_f(hi));
      int idx = (i * 256 + c) ^ ((i & 7) << 3);   // T2 XOR swizzle (ushort units)
      h1hi[idx] = hi;
      h1lo[idx] = lo;
    }
  }
  __syncthreads();

  int lane = t & 63;
  int w = t >> 6;
  int lm = lane & 15, lg = lane >> 4;

  f32x4 acc[2][2];
  f32x4 zz = {0.f, 0.f, 0.f, 0.f};
  acc[0][0] = zz; acc[0][1] = zz; acc[1][0] = zz; acc[1][1] = zz;

  int rowA0 = lm, rowA1 = 16 + lm;
  int swz0 = (rowA0 & 7) << 3, swz1 = (rowA1 & 7) << 3;

  for (int kc = 0; kc < 8; ++kc) {
    int ks = kc * 32 + lg * 8;
    int ia0 = (rowA0 * 256 + ks) ^ swz0;
    int ia1 = (rowA1 * 256 + ks) ^ swz1;
    bf16x8 ah0 = *(const bf16x8*)&h1hi[ia0];
    bf16x8 al0 = *(const bf16x8*)&h1lo[ia0];
    bf16x8 ah1 = *(const bf16x8*)&h1hi[ia1];
    bf16x8 al1 = *(const bf16x8*)&h1lo[ia1];
    size_t bb0 = ((size_t)((kc * 4 + lg) * 128) + (w * 32 + lm)) * 8;
    size_t bb1 = bb0 + 16 * 8;
    bf16x8 bh0 = *(const bf16x8*)&w2hi[bb0];
    bf16x8 bl0 = *(const bf16x8*)&w2lo[bb0];
    bf16x8 bh1 = *(const bf16x8*)&w2hi[bb1];
    bf16x8 bl1 = *(const bf16x8*)&w2lo[bb1];

    acc[0][0] = __builtin_amdgcn_mfma_f32_16x16x32_bf16(ah0, bh0, acc[0][0], 0, 0, 0);
    acc[0][1] = __builtin_amdgcn_mfma_f32_16x16x32_bf16(ah0, bh1, acc[0][1], 0, 0, 0);
    acc[1][0] = __builtin_amdgcn_mfma_f32_16x16x32_bf16(ah1, bh0, acc[1][0], 0, 0, 0);
    acc[1][1] = __builtin_amdgcn_mfma_f32_16x16x32_bf16(ah1, bh1, acc[1][1], 0, 0, 0);
    acc[0][0] = __builtin_amdgcn_mfma_f32_16x16x32_bf16(ah0, bl0, acc[0][0], 0, 0, 0);
    acc[0][1] = __builtin_amdgcn_mfma_f32_16x16x32_bf16(ah0, bl1, acc[0][1], 0, 0, 0);
    acc[1][0] = __builtin_amdgcn_mfma_f32_16x16x32_bf16(ah1, bl0, acc[1][0], 0, 0, 0);
    acc[1][1] = __builtin_amdgcn_mfma_f32_16x16x32_bf16(ah1, bl1, acc[1][1], 0, 0, 0);
    acc[0][0] = __builtin_amdgcn_mfma_f32_16x16x32_bf16(al0, bh0, acc[0][0], 0, 0, 0);
    acc[0][1] = __builtin_amdgcn_mfma_f32_16x16x32_bf16(al0, bh1, acc[0][1], 0, 0, 0);
    acc[1][0] = __builtin_amdgcn_mfma_f32_16x16x32_bf16(al1, bh0, acc[1][0], 0, 0, 0);
    acc[1][1] = __builtin_amdgcn_mfma_f32_16x16x32_bf16(al1, bh1, acc[1][1], 0, 0, 0);
  }

  // epilogue: C layout col=lane&15, row=(lane>>4)*4+reg  [verified m89/m91]
  float as0 = att_src2[w * 32 + lm], as1 = att_src2[w * 32 + 16 + lm];
  float ad0 = att_dst2[w * 32 + lm], ad1 = att_dst2[w * 32 + 16 + lm];
  #pragma unroll
  for (int mi = 0; mi < 2; ++mi) {
    float ps[4], pd[4];
    #pragma unroll
    for (int rg = 0; rg < 4; ++rg) {
      float c0v = acc[mi][0][rg], c1v = acc[mi][1][rg];
      int nrow = n0 + mi * 16 + lg * 4 + rg;
      if (nrow < N) {
        h2[(size_t)nrow * 128 + w * 32 + lm] = c0v;
        h2[(size_t)nrow * 128 + w * 32 + 16 + lm] = c1v;
      }
      ps[rg] = c0v * as0 + c1v * as1;
      pd[rg] = c0v * ad0 + c1v * ad1;
    }
    #pragma unroll
    for (int rg = 0; rg < 4; ++rg) {
      #pragma unroll
      for (int m = 8; m >= 1; m >>= 1) {
        ps[rg] += __shfl_xor(ps[rg], m, 64);
        pd[rg] += __shfl_xor(pd[rg], m, 64);
      }
      if (lm == 0) {
        int row = mi * 16 + lg * 4 + rg;
        sred_s[row][w] = ps[rg];
        sred_d[row][w] = pd[rg];
      }
    }
  }
  __syncthreads();
  if (t < 32) {
    int n = n0 + t;
    if (n < N) {
      a_src2[n] = sred_s[t][0] + sred_s[t][1] + sred_s[t][2] + sred_s[t][3];
      a_dst2[n] = sred_d[t][0] + sred_d[t][1] + sred_d[t][2] + sred_d[t][3];
    }
  }
}

// ---------------- Layer-2 aggregate -> out [N,128] ----------------
// 32-lane group per node, float4 per lane (512B coalesced gathers), 2-deep pipeline.
__global__ __launch_bounds__(256) void k_agg2(
    const float* __restrict__ h2, const float* __restrict__ b2,
    const float* __restrict__ a_src2, const float* __restrict__ a_dst2,
    const int* __restrict__ offsets, const int* __restrict__ srclist,
    float* __restrict__ out, int N)
{
  int t = threadIdx.x, lane = t & 63;
  int g = lane >> 5, r = lane & 31;
  int n = blockIdx.x * 8 + (t >> 6) * 2 + g;
  if (n >= N) return;
  int off = offsets[n], deg = offsets[n + 1] - off;
  float adn = a_dst2[n];

  int c0 = min(deg, 32);
  int s_l = 0; float a_l = -1e30f;
  if (r < c0) { s_l = srclist[off + r]; a_l = lrelu(a_src2[s_l] + adn); }
  float m = a_l;
  for (int base = 32; base < deg; base += 32)    // rare
    if (r < deg - base) m = fmaxf(m, lrelu(a_src2[srclist[off + base + r]] + adn));
  #pragma unroll
  for (int msk = 16; msk > 0; msk >>= 1) m = fmaxf(m, __shfl_xor(m, msk, 32));

  float e_l = (r < c0) ? __expf(a_l - m) : 0.f;
  float den_p = e_l;
  float4 acc = {0.f, 0.f, 0.f, 0.f};

  int j = 0;
  for (; j + 2 <= c0; j += 2) {
    int sA = __shfl(s_l, j, 32);
    int sB = __shfl(s_l, j + 1, 32);
    float eA = __shfl(e_l, j, 32);
    float eB = __shfl(e_l, j + 1, 32);
    float4 hA = *(const float4*)&h2[(size_t)sA * 128 + r * 4];
    float4 hB = *(const float4*)&h2[(size_t)sB * 128 + r * 4];
    acc.x += eA * hA.x + eB * hB.x;
    acc.y += eA * hA.y + eB * hB.y;
    acc.z += eA * hA.z + eB * hB.z;
    acc.w += eA * hA.w + eB * hB.w;
  }
  if (j < c0) {
    int sA = __shfl(s_l, j, 32);
    float eA = __shfl(e_l, j, 32);
    float4 hA = *(const float4*)&h2[(size_t)sA * 128 + r * 4];
    acc.x += eA * hA.x; acc.y += eA * hA.y; acc.z += eA * hA.z; acc.w += eA * hA.w;
  }
  for (int base = 32; base < deg; base += 32) {  // rare
    int rem = min(32, deg - base);
    int sl2 = 0; float el2 = 0.f;
    if (r < rem) { sl2 = srclist[off + base + r]; el2 = __expf(lrelu(a_src2[sl2] + adn) - m); }
    den_p += el2;
    for (int q = 0; q < rem; ++q) {
      int s = __shfl(sl2, q, 32);
      float e = __shfl(el2, q, 32);
      float4 hv = *(const float4*)&h2[(size_t)s * 128 + r * 4];
      acc.x += e * hv.x; acc.y += e * hv.y; acc.z += e * hv.z; acc.w += e * hv.w;
    }
  }
  #pragma unroll
  for (int msk = 16; msk > 0; msk >>= 1) den_p += __shfl_xor(den_p, msk, 32);
  float inv = 1.f / (den_p + 1e-16f);
  float4 bb = *(const float4*)&b2[r * 4];
  float4 o = {acc.x * inv + bb.x, acc.y * inv + bb.y, acc.z * inv + bb.z, acc.w * inv + bb.w};
  *(float4*)&out[(size_t)n * 128 + r * 4] = o;
}

extern "C" void kernel_launch(void* const* d_in, const int* in_sizes, int n_in,
                              void* d_out, int out_size, void* d_ws, size_t ws_size,
                              hipStream_t stream)
{
  const float* x        = (const float*)d_in[0];
  const int*   ei       = (const int*)d_in[1];
  const float* W1       = (const float*)d_in[2];
  const float* att_src1 = (const float*)d_in[3];
  const float* att_dst1 = (const float*)d_in[4];
  const float* b1       = (const float*)d_in[5];
  const float* W2       = (const float*)d_in[6];
  const float* att_src2 = (const float*)d_in[7];
  const float* att_dst2 = (const float*)d_in[8];
  const float* b2       = (const float*)d_in[9];
  float* out = (float*)d_out;

  int N = in_sizes[0] / 3;
  int E = in_sizes[1] / 2;

  char* p = (char*)d_ws;
  auto alloc = [&](size_t bytes) -> char* {
    char* r = p;
    p += (bytes + 255) & ~(size_t)255;
    return r;
  };
  float*    uv      = (float*)alloc(24 * 4);
  ushort_t* w2hi    = (ushort_t*)alloc(32768 * 2);
  ushort_t* w2lo    = (ushort_t*)alloc(32768 * 2);
  float*    a_src2  = (float*)alloc((size_t)N * 4);
  float*    a_dst2  = (float*)alloc((size_t)N * 4);
  int*      cnt     = (int*)alloc((size_t)N * 4);
  int*      incl    = (int*)alloc((size_t)N * 4);
  int*      csum    = (int*)alloc(64 * 4);
  int*      cbase   = (int*)alloc(64 * 4);
  int*      offsets = (int*)alloc((size_t)(N + 1) * 4);
  int*      cursor  = (int*)alloc((size_t)N * 4);
  int*      srclist = (int*)alloc((size_t)(E + N) * 4);
  float*    Xc      = (float*)alloc((size_t)16 * N * 4);
  float*    h2      = (float*)alloc((size_t)128 * N * 4);

  int nch = (N + 1023) / 1024;

  hipMemsetAsync(cnt, 0, (size_t)N * 4, stream);
  k_prep<<<17, 256, 0, stream>>>(W1, att_src1, att_dst1, W2, w2hi, w2lo, uv);
  k_count<<<(E + 255) / 256, 256, 0, stream>>>(ei, E, cnt);
  k_scan1<<<nch, 1024, 0, stream>>>(cnt, N, incl, csum);
  k_scan2<<<1, 64, 0, stream>>>(csum, nch, cbase, offsets, N);
  k_scan3<<<nch, 1024, 0, stream>>>(cnt, incl, cbase, N, offsets, cursor, srclist);
  k_fill<<<(E + 255) / 256, 256, 0, stream>>>(ei, E, cursor, srclist);
  k_agg1<<<(N + 7) / 8, 256, 0, stream>>>(x, uv, offsets, srclist, Xc, N);
  k_mm2<<<(N + 31) / 32, 256, 0, stream>>>(Xc, W1, b1, w2hi, w2lo, att_src2, att_dst2, h2, a_src2, a_dst2, N);
  k_agg2<<<(N + 7) / 8, 256, 0, stream>>>(h2, b2, a_src2, a_dst2, offsets, srclist, out, N);
}

// Round 9
// 277.913 us; speedup vs baseline: 1.5824x; 1.0544x over previous
//
#include <hip/hip_runtime.h>

#define NEG_SLOPE 0.2f
typedef unsigned short ushort_t;
typedef __attribute__((ext_vector_type(8))) short bf16x8;
typedef __attribute__((ext_vector_type(4))) float f32x4;

__device__ __forceinline__ float lrelu(float z){ return z > 0.f ? z : NEG_SLOPE * z; }

__device__ __forceinline__ ushort_t bf16_rn(float x){
  union { float f; unsigned u; } v; v.f = x;
  unsigned r = v.u + 0x7FFF + ((v.u >> 16) & 1);
  return (ushort_t)(r >> 16);
}
__device__ __forceinline__ float bf16_to_f(ushort_t h){
  union { unsigned u; float f; } v; v.u = ((unsigned)h) << 16;
  return v.f;
}

// load 4 consecutive bf16 channels of h2 row s at channel r*4, as float4
__device__ __forceinline__ float4 ld_h2q(const ushort_t* __restrict__ h2, int s, int r){
  uint2 u = *(const uint2*)&h2[(size_t)s * 128 + r * 4];
  float4 f;
  f.x = bf16_to_f((ushort_t)(u.x & 0xffffu));
  f.y = bf16_to_f((ushort_t)(u.x >> 16));
  f.z = bf16_to_f((ushort_t)(u.y & 0xffffu));
  f.w = bf16_to_f((ushort_t)(u.y >> 16));
  return f;
}

// ---------------- prep: pack W2 into bf16 hi/lo MFMA-fragment layout + u-vectors ----------------
__global__ __launch_bounds__(256) void k_prep(
    const float* __restrict__ W1, const float* __restrict__ att_src1, const float* __restrict__ att_dst1,
    const float* __restrict__ W2, ushort_t* __restrict__ w2hi, ushort_t* __restrict__ w2lo,
    float* __restrict__ uv)
{
  int gid = blockIdx.x * 256 + threadIdx.x;
  if (gid < 4096) {
    int kc = gid >> 9, g = (gid >> 7) & 3, n = gid & 127;
    #pragma unroll
    for (int e = 0; e < 8; ++e) {
      int k = kc * 32 + g * 8 + e;
      float w = W2[k * 128 + n];
      ushort_t hi = bf16_rn(w);
      ushort_t lo = bf16_rn(w - bf16_to_f(hi));
      w2hi[(size_t)gid * 8 + e] = hi;
      w2lo[(size_t)gid * 8 + e] = lo;
    }
  } else if (gid < 4120) {
    int j = gid - 4096;              // 0..23 ; uv[k*4+h] = us, uv[12+k*4+h] = ud
    int jj = j % 12;
    int k = jj >> 2, h = jj & 3;
    const float* att = (j < 12) ? att_src1 : att_dst1;
    float s = 0.f;
    for (int c = 0; c < 64; ++c) s += W1[k * 256 + h * 64 + c] * att[h * 64 + c];
    uv[j] = s;
  }
}

// pack x rows (12B) into float4 (16B) for single-load gathers
__global__ __launch_bounds__(256) void k_packx(
    const float* __restrict__ x, float4* __restrict__ xp, int N)
{
  int n = blockIdx.x * 256 + threadIdx.x;
  if (n < N) {
    float4 v = {x[n * 3], x[n * 3 + 1], x[n * 3 + 2], 0.f};
    xp[n] = v;
  }
}

// ---------------- CSR build ----------------
__global__ __launch_bounds__(256) void k_count(
    const int* __restrict__ ei, int E, int* __restrict__ cnt)
{
  int e = blockIdx.x * 256 + threadIdx.x;
  if (e < E) atomicAdd(&cnt[ei[E + e]], 1);
}

__global__ __launch_bounds__(1024) void k_scan1(
    const int* __restrict__ cnt, int N, int* __restrict__ incl, int* __restrict__ csum)
{
  __shared__ int s[1024];
  int t = threadIdx.x;
  int i = blockIdx.x * 1024 + t;
  int v = (i < N) ? cnt[i] + 1 : 0;
  s[t] = v;
  __syncthreads();
  for (int off = 1; off < 1024; off <<= 1) {
    int u = (t >= off) ? s[t - off] : 0;
    __syncthreads();
    s[t] += u;
    __syncthreads();
  }
  if (i < N) incl[i] = s[t];
  if (t == 1023) csum[blockIdx.x] = s[1023];
}

__global__ __launch_bounds__(64) void k_scan2(
    const int* __restrict__ csum, int nch, int* __restrict__ cbase,
    int* __restrict__ offsets, int N)
{
  int t = threadIdx.x;
  int v = (t < nch) ? csum[t] : 0;
  int incl = v;
  #pragma unroll
  for (int m = 1; m < 64; m <<= 1) {
    int u = __shfl_up(incl, m, 64);
    if (t >= m) incl += u;
  }
  if (t < nch) cbase[t] = incl - v;
  if (t == 63) offsets[N] = incl;
}

__global__ __launch_bounds__(1024) void k_scan3(
    const int* __restrict__ cnt, const int* __restrict__ incl, const int* __restrict__ cbase,
    int N, int* __restrict__ offsets, int* __restrict__ cursor, int* __restrict__ srclist)
{
  int i = blockIdx.x * 1024 + threadIdx.x;
  if (i < N) {
    int c = cnt[i];
    int excl = incl[i] - (c + 1) + cbase[blockIdx.x];
    offsets[i] = excl;
    cursor[i] = excl;
    srclist[excl + c] = i;  // self-loop in last slot
  }
}

__global__ __launch_bounds__(256) void k_fill(
    const int* __restrict__ ei, int E, int* __restrict__ cursor, int* __restrict__ srclist)
{
  int e = blockIdx.x * 256 + threadIdx.x;
  if (e < E) {
    int s = ei[e], d = ei[E + e];
    int pos = atomicAdd(&cursor[d], 1);
    srclist[pos] = s;
  }
}

// ---------------- Layer-1 aggregate -> X[N,16] = {den[4], xa0[4], xa1[4], xa2[4]} ----------------
// 32-lane group per node; edge scores recomputed from xp via u-vectors.
__global__ __launch_bounds__(256) void k_agg1(
    const float4* __restrict__ xp, const float* __restrict__ uv,
    const int* __restrict__ offsets, const int* __restrict__ srclist,
    float* __restrict__ X, int N)
{
  int t = threadIdx.x;
  int lane = t & 63;
  int g = lane >> 5, r = lane & 31;
  int n = blockIdx.x * 8 + (t >> 6) * 2 + g;
  if (n >= N) return;

  float us[12], ud[12];
  #pragma unroll
  for (int j = 0; j < 12; ++j) { us[j] = uv[j]; ud[j] = uv[12 + j]; }

  float4 xn = xp[n];
  float ad0 = xn.x * ud[0] + xn.y * ud[4] + xn.z * ud[8];
  float ad1 = xn.x * ud[1] + xn.y * ud[5] + xn.z * ud[9];
  float ad2 = xn.x * ud[2] + xn.y * ud[6] + xn.z * ud[10];
  float ad3 = xn.x * ud[3] + xn.y * ud[7] + xn.z * ud[11];

  int off = offsets[n];
  int deg = offsets[n + 1] - off;
  int c0 = min(deg, 32);
  float a0 = -1e30f, a1 = -1e30f, a2 = -1e30f, a3 = -1e30f;
  float x0 = 0.f, x1 = 0.f, x2 = 0.f;
  if (r < c0) {
    int s = srclist[off + r];
    float4 xs = xp[s];
    x0 = xs.x; x1 = xs.y; x2 = xs.z;
    a0 = lrelu(x0 * us[0] + x1 * us[4] + x2 * us[8]  + ad0);
    a1 = lrelu(x0 * us[1] + x1 * us[5] + x2 * us[9]  + ad1);
    a2 = lrelu(x0 * us[2] + x1 * us[6] + x2 * us[10] + ad2);
    a3 = lrelu(x0 * us[3] + x1 * us[7] + x2 * us[11] + ad3);
  }
  float m0 = a0, m1 = a1, m2 = a2, m3 = a3;
  for (int base = 32; base < deg; base += 32) {   // rare: deg>32
    if (r < deg - base) {
      int s = srclist[off + base + r];
      float4 xs = xp[s];
      m0 = fmaxf(m0, lrelu(xs.x * us[0] + xs.y * us[4] + xs.z * us[8]  + ad0));
      m1 = fmaxf(m1, lrelu(xs.x * us[1] + xs.y * us[5] + xs.z * us[9]  + ad1));
      m2 = fmaxf(m2, lrelu(xs.x * us[2] + xs.y * us[6] + xs.z * us[10] + ad2));
      m3 = fmaxf(m3, lrelu(xs.x * us[3] + xs.y * us[7] + xs.z * us[11] + ad3));
    }
  }
  #pragma unroll
  for (int msk = 16; msk > 0; msk >>= 1) {
    m0 = fmaxf(m0, __shfl_xor(m0, msk, 32)); m1 = fmaxf(m1, __shfl_xor(m1, msk, 32));
    m2 = fmaxf(m2, __shfl_xor(m2, msk, 32)); m3 = fmaxf(m3, __shfl_xor(m3, msk, 32));
  }

  float e0 = (r < c0) ? __expf(a0 - m0) : 0.f;
  float e1 = (r < c0) ? __expf(a1 - m1) : 0.f;
  float e2 = (r < c0) ? __expf(a2 - m2) : 0.f;
  float e3 = (r < c0) ? __expf(a3 - m3) : 0.f;
  float d0 = e0, d1 = e1, d2 = e2, d3 = e3;
  float xa00 = e0 * x0, xa01 = e1 * x0, xa02 = e2 * x0, xa03 = e3 * x0;
  float xa10 = e0 * x1, xa11 = e1 * x1, xa12 = e2 * x1, xa13 = e3 * x1;
  float xa20 = e0 * x2, xa21 = e1 * x2, xa22 = e2 * x2, xa23 = e3 * x2;

  for (int base = 32; base < deg; base += 32) {   // rare
    if (r < deg - base) {
      int s = srclist[off + base + r];
      float4 xs = xp[s];
      float ee0 = __expf(lrelu(xs.x * us[0] + xs.y * us[4] + xs.z * us[8]  + ad0) - m0);
      float ee1 = __expf(lrelu(xs.x * us[1] + xs.y * us[5] + xs.z * us[9]  + ad1) - m1);
      float ee2 = __expf(lrelu(xs.x * us[2] + xs.y * us[6] + xs.z * us[10] + ad2) - m2);
      float ee3 = __expf(lrelu(xs.x * us[3] + xs.y * us[7] + xs.z * us[11] + ad3) - m3);
      d0 += ee0; d1 += ee1; d2 += ee2; d3 += ee3;
      xa00 += ee0 * xs.x; xa01 += ee1 * xs.x; xa02 += ee2 * xs.x; xa03 += ee3 * xs.x;
      xa10 += ee0 * xs.y; xa11 += ee1 * xs.y; xa12 += ee2 * xs.y; xa13 += ee3 * xs.y;
      xa20 += ee0 * xs.z; xa21 += ee1 * xs.z; xa22 += ee2 * xs.z; xa23 += ee3 * xs.z;
    }
  }

  #pragma unroll
  for (int msk = 16; msk > 0; msk >>= 1) {
    d0 += __shfl_xor(d0, msk, 32); d1 += __shfl_xor(d1, msk, 32);
    d2 += __shfl_xor(d2, msk, 32); d3 += __shfl_xor(d3, msk, 32);
    xa00 += __shfl_xor(xa00, msk, 32); xa01 += __shfl_xor(xa01, msk, 32);
    xa02 += __shfl_xor(xa02, msk, 32); xa03 += __shfl_xor(xa03, msk, 32);
    xa10 += __shfl_xor(xa10, msk, 32); xa11 += __shfl_xor(xa11, msk, 32);
    xa12 += __shfl_xor(xa12, msk, 32); xa13 += __shfl_xor(xa13, msk, 32);
    xa20 += __shfl_xor(xa20, msk, 32); xa21 += __shfl_xor(xa21, msk, 32);
    xa22 += __shfl_xor(xa22, msk, 32); xa23 += __shfl_xor(xa23, msk, 32);
  }

  if (r < 16) {
    int j = r;
    float v =
      j == 0 ? d0 : j == 1 ? d1 : j == 2 ? d2 : j == 3 ? d3 :
      j == 4 ? xa00 : j == 5 ? xa01 : j == 6 ? xa02 : j == 7 ? xa03 :
      j == 8 ? xa10 : j == 9 ? xa11 : j == 10 ? xa12 : j == 11 ? xa13 :
      j == 12 ? xa20 : j == 13 ? xa21 : j == 14 ? xa22 : xa23;
    X[(size_t)n * 16 + j] = v;
  }
}

// ---------------- Fused expand + split-bf16 MFMA GEMM + layer-2 scores ----------------
// h2 is now stored as bf16 (halves the k_agg2 gather traffic).
__global__ __launch_bounds__(256) void k_mm2(
    const float* __restrict__ Xc, const float* __restrict__ W1, const float* __restrict__ b1,
    const ushort_t* __restrict__ w2hi, const ushort_t* __restrict__ w2lo,
    const float* __restrict__ att_src2, const float* __restrict__ att_dst2,
    ushort_t* __restrict__ h2, float* __restrict__ a_src2, float* __restrict__ a_dst2, int N)
{
  __shared__ ushort_t h1hi[32 * 256];
  __shared__ ushort_t h1lo[32 * 256];
  __shared__ float Xs[512];
  __shared__ float W1s[768];
  __shared__ float b1s[256];
  __shared__ float invs[128];
  __shared__ float sred_s[32][4];
  __shared__ float sred_d[32][4];

  int t = threadIdx.x;
  int n0 = blockIdx.x * 32;

  for (int i = t; i < 768; i += 256) W1s[i] = W1[i];
  b1s[t] = b1[t];
  for (int i = t; i < 512; i += 256) {
    int idx = n0 * 16 + i;
    Xs[i] = (idx < N * 16) ? Xc[idx] : 0.f;
  }
  __syncthreads();
  if (t < 128) invs[t] = 1.f / (Xs[(t >> 2) * 16 + (t & 3)] + 1e-16f);
  __syncthreads();

  // expansion: thread t owns channel c=t for all 32 nodes
  {
    int c = t, h = t >> 6;
    float w0 = W1s[c], w1 = W1s[256 + c], w2v = W1s[512 + c], bb = b1s[c];
    #pragma unroll 4
    for (int i = 0; i < 32; ++i) {
      float inv = invs[i * 4 + h];
      float X0 = Xs[i * 16 + 4 + h] * inv;
      float X1 = Xs[i * 16 + 8 + h] * inv;
      float X2 = Xs[i * 16 + 12 + h] * inv;
      float v = fmaf(w0, X0, fmaf(w1, X1, fmaf(w2v, X2, bb)));
      v = v > 0.f ? v : __expf(v) - 1.f;      // ELU
      ushort_t hi = bf16_rn(v);
      ushort_t lo = bf16_rn(v - bf16_to_f(hi));
      int idx = (i * 256 + c) ^ ((i & 7) << 3);   // T2 XOR swizzle (ushort units)
      h1hi[idx] = hi;
      h1lo[idx] = lo;
    }
  }
  __syncthreads();

  int lane = t & 63;
  int w = t >> 6;
  int lm = lane & 15, lg = lane >> 4;

  f32x4 acc[2][2];
  f32x4 zz = {0.f, 0.f, 0.f, 0.f};
  acc[0][0] = zz; acc[0][1] = zz; acc[1][0] = zz; acc[1][1] = zz;

  int rowA0 = lm, rowA1 = 16 + lm;
  int swz0 = (rowA0 & 7) << 3, swz1 = (rowA1 & 7) << 3;

  for (int kc = 0; kc < 8; ++kc) {
    int ks = kc * 32 + lg * 8;
    int ia0 = (rowA0 * 256 + ks) ^ swz0;
    int ia1 = (rowA1 * 256 + ks) ^ swz1;
    bf16x8 ah0 = *(const bf16x8*)&h1hi[ia0];
    bf16x8 al0 = *(const bf16x8*)&h1lo[ia0];
    bf16x8 ah1 = *(const bf16x8*)&h1hi[ia1];
    bf16x8 al1 = *(const bf16x8*)&h1lo[ia1];
    size_t bb0 = ((size_t)((kc * 4 + lg) * 128) + (w * 32 + lm)) * 8;
    size_t bb1 = bb0 + 16 * 8;
    bf16x8 bh0 = *(const bf16x8*)&w2hi[bb0];
    bf16x8 bl0 = *(const bf16x8*)&w2lo[bb0];
    bf16x8 bh1 = *(const bf16x8*)&w2hi[bb1];
    bf16x8 bl1 = *(const bf16x8*)&w2lo[bb1];

    acc[0][0] = __builtin_amdgcn_mfma_f32_16x16x32_bf16(ah0, bh0, acc[0][0], 0, 0, 0);
    acc[0][1] = __builtin_amdgcn_mfma_f32_16x16x32_bf16(ah0, bh1, acc[0][1], 0, 0, 0);
    acc[1][0] = __builtin_amdgcn_mfma_f32_16x16x32_bf16(ah1, bh0, acc[1][0], 0, 0, 0);
    acc[1][1] = __builtin_amdgcn_mfma_f32_16x16x32_bf16(ah1, bh1, acc[1][1], 0, 0, 0);
    acc[0][0] = __builtin_amdgcn_mfma_f32_16x16x32_bf16(ah0, bl0, acc[0][0], 0, 0, 0);
    acc[0][1] = __builtin_amdgcn_mfma_f32_16x16x32_bf16(ah0, bl1, acc[0][1], 0, 0, 0);
    acc[1][0] = __builtin_amdgcn_mfma_f32_16x16x32_bf16(ah1, bl0, acc[1][0], 0, 0, 0);
    acc[1][1] = __builtin_amdgcn_mfma_f32_16x16x32_bf16(ah1, bl1, acc[1][1], 0, 0, 0);
    acc[0][0] = __builtin_amdgcn_mfma_f32_16x16x32_bf16(al0, bh0, acc[0][0], 0, 0, 0);
    acc[0][1] = __builtin_amdgcn_mfma_f32_16x16x32_bf16(al0, bh1, acc[0][1], 0, 0, 0);
    acc[1][0] = __builtin_amdgcn_mfma_f32_16x16x32_bf16(al1, bh0, acc[1][0], 0, 0, 0);
    acc[1][1] = __builtin_amdgcn_mfma_f32_16x16x32_bf16(al1, bh1, acc[1][1], 0, 0, 0);
  }

  // epilogue: C layout col=lane&15, row=(lane>>4)*4+reg  [verified m89/m91]
  float as0 = att_src2[w * 32 + lm], as1 = att_src2[w * 32 + 16 + lm];
  float ad0 = att_dst2[w * 32 + lm], ad1 = att_dst2[w * 32 + 16 + lm];
  #pragma unroll
  for (int mi = 0; mi < 2; ++mi) {
    float ps[4], pd[4];
    #pragma unroll
    for (int rg = 0; rg < 4; ++rg) {
      float c0v = acc[mi][0][rg], c1v = acc[mi][1][rg];
      int nrow = n0 + mi * 16 + lg * 4 + rg;
      if (nrow < N) {
        h2[(size_t)nrow * 128 + w * 32 + lm] = bf16_rn(c0v);
        h2[(size_t)nrow * 128 + w * 32 + 16 + lm] = bf16_rn(c1v);
      }
      ps[rg] = c0v * as0 + c1v * as1;
      pd[rg] = c0v * ad0 + c1v * ad1;
    }
    #pragma unroll
    for (int rg = 0; rg < 4; ++rg) {
      #pragma unroll
      for (int m = 8; m >= 1; m >>= 1) {
        ps[rg] += __shfl_xor(ps[rg], m, 64);
        pd[rg] += __shfl_xor(pd[rg], m, 64);
      }
      if (lm == 0) {
        int row = mi * 16 + lg * 4 + rg;
        sred_s[row][w] = ps[rg];
        sred_d[row][w] = pd[rg];
      }
    }
  }
  __syncthreads();
  if (t < 32) {
    int n = n0 + t;
    if (n < N) {
      a_src2[n] = sred_s[t][0] + sred_s[t][1] + sred_s[t][2] + sred_s[t][3];
      a_dst2[n] = sred_d[t][0] + sred_d[t][1] + sred_d[t][2] + sred_d[t][3];
    }
  }
}

// ---------------- Layer-2 aggregate -> out [N,128] ----------------
// 32-lane group per node; bf16 h2 gather (256B/edge), 4-deep pipelined edge loop.
__global__ __launch_bounds__(256) void k_agg2(
    const ushort_t* __restrict__ h2, const float* __restrict__ b2,
    const float* __restrict__ a_src2, const float* __restrict__ a_dst2,
    const int* __restrict__ offsets, const int* __restrict__ srclist,
    float* __restrict__ out, int N)
{
  int t = threadIdx.x, lane = t & 63;
  int g = lane >> 5, r = lane & 31;
  int n = blockIdx.x * 8 + (t >> 6) * 2 + g;
  if (n >= N) return;
  int off = offsets[n], deg = offsets[n + 1] - off;
  float adn = a_dst2[n];

  int c0 = min(deg, 32);
  int s_l = 0; float a_l = -1e30f;
  if (r < c0) { s_l = srclist[off + r]; a_l = lrelu(a_src2[s_l] + adn); }
  float m = a_l;
  for (int base = 32; base < deg; base += 32)    // rare
    if (r < deg - base) m = fmaxf(m, lrelu(a_src2[srclist[off + base + r]] + adn));
  #pragma unroll
  for (int msk = 16; msk > 0; msk >>= 1) m = fmaxf(m, __shfl_xor(m, msk, 32));

  float e_l = (r < c0) ? __expf(a_l - m) : 0.f;
  float den_p = e_l;
  float4 acc = {0.f, 0.f, 0.f, 0.f};

  int j = 0;
  for (; j + 4 <= c0; j += 4) {
    int   sA = __shfl(s_l, j, 32),     sB = __shfl(s_l, j + 1, 32);
    int   sC = __shfl(s_l, j + 2, 32), sD = __shfl(s_l, j + 3, 32);
    float eA = __shfl(e_l, j, 32),     eB = __shfl(e_l, j + 1, 32);
    float eC = __shfl(e_l, j + 2, 32), eD = __shfl(e_l, j + 3, 32);
    float4 hA = ld_h2q(h2, sA, r);
    float4 hB = ld_h2q(h2, sB, r);
    float4 hC = ld_h2q(h2, sC, r);
    float4 hD = ld_h2q(h2, sD, r);
    acc.x += eA * hA.x + eB * hB.x + eC * hC.x + eD * hD.x;
    acc.y += eA * hA.y + eB * hB.y + eC * hC.y + eD * hD.y;
    acc.z += eA * hA.z + eB * hB.z + eC * hC.z + eD * hD.z;
    acc.w += eA * hA.w + eB * hB.w + eC * hC.w + eD * hD.w;
  }
  for (; j < c0; ++j) {
    int sA = __shfl(s_l, j, 32);
    float eA = __shfl(e_l, j, 32);
    float4 hA = ld_h2q(h2, sA, r);
    acc.x += eA * hA.x; acc.y += eA * hA.y; acc.z += eA * hA.z; acc.w += eA * hA.w;
  }
  for (int base = 32; base < deg; base += 32) {  // rare
    int rem = min(32, deg - base);
    int sl2 = 0; float el2 = 0.f;
    if (r < rem) { sl2 = srclist[off + base + r]; el2 = __expf(lrelu(a_src2[sl2] + adn) - m); }
    den_p += el2;
    for (int q = 0; q < rem; ++q) {
      int s = __shfl(sl2, q, 32);
      float e = __shfl(el2, q, 32);
      float4 hv = ld_h2q(h2, s, r);
      acc.x += e * hv.x; acc.y += e * hv.y; acc.z += e * hv.z; acc.w += e * hv.w;
    }
  }
  #pragma unroll
  for (int msk = 16; msk > 0; msk >>= 1) den_p += __shfl_xor(den_p, msk, 32);
  float inv = 1.f / (den_p + 1e-16f);
  float4 bb = *(const float4*)&b2[r * 4];
  float4 o = {acc.x * inv + bb.x, acc.y * inv + bb.y, acc.z * inv + bb.z, acc.w * inv + bb.w};
  *(float4*)&out[(size_t)n * 128 + r * 4] = o;
}

extern "C" void kernel_launch(void* const* d_in, const int* in_sizes, int n_in,
                              void* d_out, int out_size, void* d_ws, size_t ws_size,
                              hipStream_t stream)
{
  const float* x        = (const float*)d_in[0];
  const int*   ei       = (const int*)d_in[1];
  const float* W1       = (const float*)d_in[2];
  const float* att_src1 = (const float*)d_in[3];
  const float* att_dst1 = (const float*)d_in[4];
  const float* b1       = (const float*)d_in[5];
  const float* W2       = (const float*)d_in[6];
  const float* att_src2 = (const float*)d_in[7];
  const float* att_dst2 = (const float*)d_in[8];
  const float* b2       = (const float*)d_in[9];
  float* out = (float*)d_out;

  int N = in_sizes[0] / 3;
  int E = in_sizes[1] / 2;

  char* p = (char*)d_ws;
  auto alloc = [&](size_t bytes) -> char* {
    char* r = p;
    p += (bytes + 255) & ~(size_t)255;
    return r;
  };
  float*    uv      = (float*)alloc(24 * 4);
  ushort_t* w2hi    = (ushort_t*)alloc(32768 * 2);
  ushort_t* w2lo    = (ushort_t*)alloc(32768 * 2);
  float4*   xp      = (float4*)alloc((size_t)N * 16);
  float*    a_src2  = (float*)alloc((size_t)N * 4);
  float*    a_dst2  = (float*)alloc((size_t)N * 4);
  int*      cnt     = (int*)alloc((size_t)N * 4);
  int*      incl    = (int*)alloc((size_t)N * 4);
  int*      csum    = (int*)alloc(64 * 4);
  int*      cbase   = (int*)alloc(64 * 4);
  int*      offsets = (int*)alloc((size_t)(N + 1) * 4);
  int*      cursor  = (int*)alloc((size_t)N * 4);
  int*      srclist = (int*)alloc((size_t)(E + N) * 4);
  float*    Xc      = (float*)alloc((size_t)16 * N * 4);
  ushort_t* h2      = (ushort_t*)alloc((size_t)128 * N * 2);

  int nch = (N + 1023) / 1024;

  hipMemsetAsync(cnt, 0, (size_t)N * 4, stream);
  k_prep<<<17, 256, 0, stream>>>(W1, att_src1, att_dst1, W2, w2hi, w2lo, uv);
  k_packx<<<(N + 255) / 256, 256, 0, stream>>>(x, xp, N);
  k_count<<<(E + 255) / 256, 256, 0, stream>>>(ei, E, cnt);
  k_scan1<<<nch, 1024, 0, stream>>>(cnt, N, incl, csum);
  k_scan2<<<1, 64, 0, stream>>>(csum, nch, cbase, offsets, N);
  k_scan3<<<nch, 1024, 0, stream>>>(cnt, incl, cbase, N, offsets, cursor, srclist);
  k_fill<<<(E + 255) / 256, 256, 0, stream>>>(ei, E, cursor, srclist);
  k_agg1<<<(N + 7) / 8, 256, 0, stream>>>(xp, uv, offsets, srclist, Xc, N);
  k_mm2<<<(N + 31) / 32, 256, 0, stream>>>(Xc, W1, b1, w2hi, w2lo, att_src2, att_dst2, h2, a_src2, a_dst2, N);
  k_agg2<<<(N + 7) / 8, 256, 0, stream>>>(h2, b2, a_src2, a_dst2, offsets, srclist, out, N);
}

// Round 10
// 262.790 us; speedup vs baseline: 1.6734x; 1.0575x over previous
//
#include <hip/hip_runtime.h>

#define NEG_SLOPE 0.2f
typedef unsigned short ushort_t;
typedef __attribute__((ext_vector_type(8))) short bf16x8;
typedef __attribute__((ext_vector_type(4))) float f32x4;

__device__ __forceinline__ float lrelu(float z){ return z > 0.f ? z : NEG_SLOPE * z; }

__device__ __forceinline__ ushort_t bf16_rn(float x){
  union { float f; unsigned u; } v; v.f = x;
  unsigned r = v.u + 0x7FFF + ((v.u >> 16) & 1);
  return (ushort_t)(r >> 16);
}
__device__ __forceinline__ float bf16_to_f(ushort_t h){
  union { unsigned u; float f; } v; v.u = ((unsigned)h) << 16;
  return v.f;
}

// load 4 consecutive bf16 channels of h2 row s at channel r*4, as float4
__device__ __forceinline__ float4 ld_h2q(const ushort_t* __restrict__ h2, int s, int r){
  uint2 u = *(const uint2*)&h2[(size_t)s * 128 + r * 4];
  float4 f;
  f.x = bf16_to_f((ushort_t)(u.x & 0xffffu));
  f.y = bf16_to_f((ushort_t)(u.x >> 16));
  f.z = bf16_to_f((ushort_t)(u.y & 0xffffu));
  f.w = bf16_to_f((ushort_t)(u.y >> 16));
  return f;
}

// ---------------- prep: pack W2 into bf16 hi/lo MFMA-fragment layout + u-vectors ----------------
__global__ __launch_bounds__(256) void k_prep(
    const float* __restrict__ W1, const float* __restrict__ att_src1, const float* __restrict__ att_dst1,
    const float* __restrict__ W2, ushort_t* __restrict__ w2hi, ushort_t* __restrict__ w2lo,
    float* __restrict__ uv)
{
  int gid = blockIdx.x * 256 + threadIdx.x;
  if (gid < 4096) {
    int kc = gid >> 9, g = (gid >> 7) & 3, n = gid & 127;
    #pragma unroll
    for (int e = 0; e < 8; ++e) {
      int k = kc * 32 + g * 8 + e;
      float w = W2[k * 128 + n];
      ushort_t hi = bf16_rn(w);
      ushort_t lo = bf16_rn(w - bf16_to_f(hi));
      w2hi[(size_t)gid * 8 + e] = hi;
      w2lo[(size_t)gid * 8 + e] = lo;
    }
  } else if (gid < 4120) {
    int j = gid - 4096;              // 0..23 ; uv[k*4+h] = us, uv[12+k*4+h] = ud
    int jj = j % 12;
    int k = jj >> 2, h = jj & 3;
    const float* att = (j < 12) ? att_src1 : att_dst1;
    float s = 0.f;
    for (int c = 0; c < 64; ++c) s += W1[k * 256 + h * 64 + c] * att[h * 64 + c];
    uv[j] = s;
  }
}

// pack x rows (12B) into float4 (16B) for single-load gathers
__global__ __launch_bounds__(256) void k_packx(
    const float* __restrict__ x, float4* __restrict__ xp, int N)
{
  int n = blockIdx.x * 256 + threadIdx.x;
  if (n < N) {
    float4 v = {x[n * 3], x[n * 3 + 1], x[n * 3 + 2], 0.f};
    xp[n] = v;
  }
}

// ---------------- CSR build ----------------
// 8 edges/thread: independent fire-and-forget atomics
__global__ __launch_bounds__(256) void k_count(
    const int* __restrict__ ei, int E, int* __restrict__ cnt)
{
  int e0 = (blockIdx.x * 256 + threadIdx.x) * 8;
  if (e0 + 8 <= E) {
    #pragma unroll
    for (int k = 0; k < 8; ++k) {
      int d = ei[E + e0 + k];
      atomicAdd(&cnt[d], 1);
    }
  } else {
    for (int e = e0; e < E; ++e) atomicAdd(&cnt[ei[E + e]], 1);
  }
}

__global__ __launch_bounds__(1024) void k_scan1(
    const int* __restrict__ cnt, int N, int* __restrict__ incl, int* __restrict__ csum)
{
  __shared__ int s[1024];
  int t = threadIdx.x;
  int i = blockIdx.x * 1024 + t;
  int v = (i < N) ? cnt[i] + 1 : 0;
  s[t] = v;
  __syncthreads();
  for (int off = 1; off < 1024; off <<= 1) {
    int u = (t >= off) ? s[t - off] : 0;
    __syncthreads();
    s[t] += u;
    __syncthreads();
  }
  if (i < N) incl[i] = s[t];
  if (t == 1023) csum[blockIdx.x] = s[1023];
}

__global__ __launch_bounds__(64) void k_scan2(
    const int* __restrict__ csum, int nch, int* __restrict__ cbase,
    int* __restrict__ offsets, int N)
{
  int t = threadIdx.x;
  int v = (t < nch) ? csum[t] : 0;
  int incl = v;
  #pragma unroll
  for (int m = 1; m < 64; m <<= 1) {
    int u = __shfl_up(incl, m, 64);
    if (t >= m) incl += u;
  }
  if (t < nch) cbase[t] = incl - v;
  if (t == 63) offsets[N] = incl;
}

__global__ __launch_bounds__(1024) void k_scan3(
    const int* __restrict__ cnt, const int* __restrict__ incl, const int* __restrict__ cbase,
    int N, int* __restrict__ offsets, int* __restrict__ cursor, int* __restrict__ srclist)
{
  int i = blockIdx.x * 1024 + threadIdx.x;
  if (i < N) {
    int c = cnt[i];
    int excl = incl[i] - (c + 1) + cbase[blockIdx.x];
    offsets[i] = excl;
    cursor[i] = excl;
    srclist[excl + c] = i;  // self-loop in last slot
  }
}

// 8 edges/thread: 8 independent atomic->store chains in flight per thread
__global__ __launch_bounds__(256) void k_fill(
    const int* __restrict__ ei, int E, int* __restrict__ cursor, int* __restrict__ srclist)
{
  int e0 = (blockIdx.x * 256 + threadIdx.x) * 8;
  if (e0 + 8 <= E) {
    int s[8], p[8];
    #pragma unroll
    for (int k = 0; k < 8; ++k) s[k] = ei[e0 + k];
    int d[8];
    #pragma unroll
    for (int k = 0; k < 8; ++k) d[k] = ei[E + e0 + k];
    #pragma unroll
    for (int k = 0; k < 8; ++k) p[k] = atomicAdd(&cursor[d[k]], 1);
    #pragma unroll
    for (int k = 0; k < 8; ++k) srclist[p[k]] = s[k];
  } else {
    for (int e = e0; e < E; ++e) {
      int pos = atomicAdd(&cursor[ei[E + e]], 1);
      srclist[pos] = ei[e];
    }
  }
}

// ---------------- Layer-1 aggregate -> X[N,16] = {den[4], xa0[4], xa1[4], xa2[4]} ----------------
// 32-lane group per node; edge scores recomputed from xp via u-vectors.
__global__ __launch_bounds__(256) void k_agg1(
    const float4* __restrict__ xp, const float* __restrict__ uv,
    const int* __restrict__ offsets, const int* __restrict__ srclist,
    float* __restrict__ X, int N)
{
  int t = threadIdx.x;
  int lane = t & 63;
  int g = lane >> 5, r = lane & 31;
  int n = blockIdx.x * 8 + (t >> 6) * 2 + g;
  if (n >= N) return;

  float us[12], ud[12];
  #pragma unroll
  for (int j = 0; j < 12; ++j) { us[j] = uv[j]; ud[j] = uv[12 + j]; }

  float4 xn = xp[n];
  float ad0 = xn.x * ud[0] + xn.y * ud[4] + xn.z * ud[8];
  float ad1 = xn.x * ud[1] + xn.y * ud[5] + xn.z * ud[9];
  float ad2 = xn.x * ud[2] + xn.y * ud[6] + xn.z * ud[10];
  float ad3 = xn.x * ud[3] + xn.y * ud[7] + xn.z * ud[11];

  int off = offsets[n];
  int deg = offsets[n + 1] - off;
  int c0 = min(deg, 32);
  float a0 = -1e30f, a1 = -1e30f, a2 = -1e30f, a3 = -1e30f;
  float x0 = 0.f, x1 = 0.f, x2 = 0.f;
  if (r < c0) {
    int s = srclist[off + r];
    float4 xs = xp[s];
    x0 = xs.x; x1 = xs.y; x2 = xs.z;
    a0 = lrelu(x0 * us[0] + x1 * us[4] + x2 * us[8]  + ad0);
    a1 = lrelu(x0 * us[1] + x1 * us[5] + x2 * us[9]  + ad1);
    a2 = lrelu(x0 * us[2] + x1 * us[6] + x2 * us[10] + ad2);
    a3 = lrelu(x0 * us[3] + x1 * us[7] + x2 * us[11] + ad3);
  }
  float m0 = a0, m1 = a1, m2 = a2, m3 = a3;
  for (int base = 32; base < deg; base += 32) {   // rare: deg>32
    if (r < deg - base) {
      int s = srclist[off + base + r];
      float4 xs = xp[s];
      m0 = fmaxf(m0, lrelu(xs.x * us[0] + xs.y * us[4] + xs.z * us[8]  + ad0));
      m1 = fmaxf(m1, lrelu(xs.x * us[1] + xs.y * us[5] + xs.z * us[9]  + ad1));
      m2 = fmaxf(m2, lrelu(xs.x * us[2] + xs.y * us[6] + xs.z * us[10] + ad2));
      m3 = fmaxf(m3, lrelu(xs.x * us[3] + xs.y * us[7] + xs.z * us[11] + ad3));
    }
  }
  #pragma unroll
  for (int msk = 16; msk > 0; msk >>= 1) {
    m0 = fmaxf(m0, __shfl_xor(m0, msk, 32)); m1 = fmaxf(m1, __shfl_xor(m1, msk, 32));
    m2 = fmaxf(m2, __shfl_xor(m2, msk, 32)); m3 = fmaxf(m3, __shfl_xor(m3, msk, 32));
  }

  float e0 = (r < c0) ? __expf(a0 - m0) : 0.f;
  float e1 = (r < c0) ? __expf(a1 - m1) : 0.f;
  float e2 = (r < c0) ? __expf(a2 - m2) : 0.f;
  float e3 = (r < c0) ? __expf(a3 - m3) : 0.f;
  float d0 = e0, d1 = e1, d2 = e2, d3 = e3;
  float xa00 = e0 * x0, xa01 = e1 * x0, xa02 = e2 * x0, xa03 = e3 * x0;
  float xa10 = e0 * x1, xa11 = e1 * x1, xa12 = e2 * x1, xa13 = e3 * x1;
  float xa20 = e0 * x2, xa21 = e1 * x2, xa22 = e2 * x2, xa23 = e3 * x2;

  for (int base = 32; base < deg; base += 32) {   // rare
    if (r < deg - base) {
      int s = srclist[off + base + r];
      float4 xs = xp[s];
      float ee0 = __expf(lrelu(xs.x * us[0] + xs.y * us[4] + xs.z * us[8]  + ad0) - m0);
      float ee1 = __expf(lrelu(xs.x * us[1] + xs.y * us[5] + xs.z * us[9]  + ad1) - m1);
      float ee2 = __expf(lrelu(xs.x * us[2] + xs.y * us[6] + xs.z * us[10] + ad2) - m2);
      float ee3 = __expf(lrelu(xs.x * us[3] + xs.y * us[7] + xs.z * us[11] + ad3) - m3);
      d0 += ee0; d1 += ee1; d2 += ee2; d3 += ee3;
      xa00 += ee0 * xs.x; xa01 += ee1 * xs.x; xa02 += ee2 * xs.x; xa03 += ee3 * xs.x;
      xa10 += ee0 * xs.y; xa11 += ee1 * xs.y; xa12 += ee2 * xs.y; xa13 += ee3 * xs.y;
      xa20 += ee0 * xs.z; xa21 += ee1 * xs.z; xa22 += ee2 * xs.z; xa23 += ee3 * xs.z;
    }
  }

  #pragma unroll
  for (int msk = 16; msk > 0; msk >>= 1) {
    d0 += __shfl_xor(d0, msk, 32); d1 += __shfl_xor(d1, msk, 32);
    d2 += __shfl_xor(d2, msk, 32); d3 += __shfl_xor(d3, msk, 32);
    xa00 += __shfl_xor(xa00, msk, 32); xa01 += __shfl_xor(xa01, msk, 32);
    xa02 += __shfl_xor(xa02, msk, 32); xa03 += __shfl_xor(xa03, msk, 32);
    xa10 += __shfl_xor(xa10, msk, 32); xa11 += __shfl_xor(xa11, msk, 32);
    xa12 += __shfl_xor(xa12, msk, 32); xa13 += __shfl_xor(xa13, msk, 32);
    xa20 += __shfl_xor(xa20, msk, 32); xa21 += __shfl_xor(xa21, msk, 32);
    xa22 += __shfl_xor(xa22, msk, 32); xa23 += __shfl_xor(xa23, msk, 32);
  }

  if (r < 16) {
    int j = r;
    float v =
      j == 0 ? d0 : j == 1 ? d1 : j == 2 ? d2 : j == 3 ? d3 :
      j == 4 ? xa00 : j == 5 ? xa01 : j == 6 ? xa02 : j == 7 ? xa03 :
      j == 8 ? xa10 : j == 9 ? xa11 : j == 10 ? xa12 : j == 11 ? xa13 :
      j == 12 ? xa20 : j == 13 ? xa21 : j == 14 ? xa22 : xa23;
    X[(size_t)n * 16 + j] = v;
  }
}

// ---------------- Fused expand + split-bf16 MFMA GEMM + layer-2 scores ----------------
// h2 stored as bf16 (halves the k_agg2 gather traffic).
__global__ __launch_bounds__(256) void k_mm2(
    const float* __restrict__ Xc, const float* __restrict__ W1, const float* __restrict__ b1,
    const ushort_t* __restrict__ w2hi, const ushort_t* __restrict__ w2lo,
    const float* __restrict__ att_src2, const float* __restrict__ att_dst2,
    ushort_t* __restrict__ h2, float* __restrict__ a_src2, float* __restrict__ a_dst2, int N)
{
  __shared__ ushort_t h1hi[32 * 256];
  __shared__ ushort_t h1lo[32 * 256];
  __shared__ float Xs[512];
  __shared__ float W1s[768];
  __shared__ float b1s[256];
  __shared__ float invs[128];
  __shared__ float sred_s[32][4];
  __shared__ float sred_d[32][4];

  int t = threadIdx.x;
  int n0 = blockIdx.x * 32;

  for (int i = t; i < 768; i += 256) W1s[i] = W1[i];
  b1s[t] = b1[t];
  for (int i = t; i < 512; i += 256) {
    int idx = n0 * 16 + i;
    Xs[i] = (idx < N * 16) ? Xc[idx] : 0.f;
  }
  __syncthreads();
  if (t < 128) invs[t] = 1.f / (Xs[(t >> 2) * 16 + (t & 3)] + 1e-16f);
  __syncthreads();

  // expansion: thread t owns channel c=t for all 32 nodes
  {
    int c = t, h = t >> 6;
    float w0 = W1s[c], w1 = W1s[256 + c], w2v = W1s[512 + c], bb = b1s[c];
    #pragma unroll 4
    for (int i = 0; i < 32; ++i) {
      float inv = invs[i * 4 + h];
      float X0 = Xs[i * 16 + 4 + h] * inv;
      float X1 = Xs[i * 16 + 8 + h] * inv;
      float X2 = Xs[i * 16 + 12 + h] * inv;
      float v = fmaf(w0, X0, fmaf(w1, X1, fmaf(w2v, X2, bb)));
      v = v > 0.f ? v : __expf(v) - 1.f;      // ELU
      ushort_t hi = bf16_rn(v);
      ushort_t lo = bf16_rn(v - bf16_to_f(hi));
      int idx = (i * 256 + c) ^ ((i & 7) << 3);   // T2 XOR swizzle (ushort units)
      h1hi[idx] = hi;
      h1lo[idx] = lo;
    }
  }
  __syncthreads();

  int lane = t & 63;
  int w = t >> 6;
  int lm = lane & 15, lg = lane >> 4;

  f32x4 acc[2][2];
  f32x4 zz = {0.f, 0.f, 0.f, 0.f};
  acc[0][0] = zz; acc[0][1] = zz; acc[1][0] = zz; acc[1][1] = zz;

  int rowA0 = lm, rowA1 = 16 + lm;
  int swz0 = (rowA0 & 7) << 3, swz1 = (rowA1 & 7) << 3;

  for (int kc = 0; kc < 8; ++kc) {
    int ks = kc * 32 + lg * 8;
    int ia0 = (rowA0 * 256 + ks) ^ swz0;
    int ia1 = (rowA1 * 256 + ks) ^ swz1;
    bf16x8 ah0 = *(const bf16x8*)&h1hi[ia0];
    bf16x8 al0 = *(const bf16x8*)&h1lo[ia0];
    bf16x8 ah1 = *(const bf16x8*)&h1hi[ia1];
    bf16x8 al1 = *(const bf16x8*)&h1lo[ia1];
    size_t bb0 = ((size_t)((kc * 4 + lg) * 128) + (w * 32 + lm)) * 8;
    size_t bb1 = bb0 + 16 * 8;
    bf16x8 bh0 = *(const bf16x8*)&w2hi[bb0];
    bf16x8 bl0 = *(const bf16x8*)&w2lo[bb0];
    bf16x8 bh1 = *(const bf16x8*)&w2hi[bb1];
    bf16x8 bl1 = *(const bf16x8*)&w2lo[bb1];

    acc[0][0] = __builtin_amdgcn_mfma_f32_16x16x32_bf16(ah0, bh0, acc[0][0], 0, 0, 0);
    acc[0][1] = __builtin_amdgcn_mfma_f32_16x16x32_bf16(ah0, bh1, acc[0][1], 0, 0, 0);
    acc[1][0] = __builtin_amdgcn_mfma_f32_16x16x32_bf16(ah1, bh0, acc[1][0], 0, 0, 0);
    acc[1][1] = __builtin_amdgcn_mfma_f32_16x16x32_bf16(ah1, bh1, acc[1][1], 0, 0, 0);
    acc[0][0] = __builtin_amdgcn_mfma_f32_16x16x32_bf16(ah0, bl0, acc[0][0], 0, 0, 0);
    acc[0][1] = __builtin_amdgcn_mfma_f32_16x16x32_bf16(ah0, bl1, acc[0][1], 0, 0, 0);
    acc[1][0] = __builtin_amdgcn_mfma_f32_16x16x32_bf16(ah1, bl0, acc[1][0], 0, 0, 0);
    acc[1][1] = __builtin_amdgcn_mfma_f32_16x16x32_bf16(ah1, bl1, acc[1][1], 0, 0, 0);
    acc[0][0] = __builtin_amdgcn_mfma_f32_16x16x32_bf16(al0, bh0, acc[0][0], 0, 0, 0);
    acc[0][1] = __builtin_amdgcn_mfma_f32_16x16x32_bf16(al0, bh1, acc[0][1], 0, 0, 0);
    acc[1][0] = __builtin_amdgcn_mfma_f32_16x16x32_bf16(al1, bh0, acc[1][0], 0, 0, 0);
    acc[1][1] = __builtin_amdgcn_mfma_f32_16x16x32_bf16(al1, bh1, acc[1][1], 0, 0, 0);
  }

  // epilogue: C layout col=lane&15, row=(lane>>4)*4+reg  [verified m89/m91]
  float as0 = att_src2[w * 32 + lm], as1 = att_src2[w * 32 + 16 + lm];
  float ad0 = att_dst2[w * 32 + lm], ad1 = att_dst2[w * 32 + 16 + lm];
  #pragma unroll
  for (int mi = 0; mi < 2; ++mi) {
    float ps[4], pd[4];
    #pragma unroll
    for (int rg = 0; rg < 4; ++rg) {
      float c0v = acc[mi][0][rg], c1v = acc[mi][1][rg];
      int nrow = n0 + mi * 16 + lg * 4 + rg;
      if (nrow < N) {
        h2[(size_t)nrow * 128 + w * 32 + lm] = bf16_rn(c0v);
        h2[(size_t)nrow * 128 + w * 32 + 16 + lm] = bf16_rn(c1v);
      }
      ps[rg] = c0v * as0 + c1v * as1;
      pd[rg] = c0v * ad0 + c1v * ad1;
    }
    #pragma unroll
    for (int rg = 0; rg < 4; ++rg) {
      #pragma unroll
      for (int m = 8; m >= 1; m >>= 1) {
        ps[rg] += __shfl_xor(ps[rg], m, 64);
        pd[rg] += __shfl_xor(pd[rg], m, 64);
      }
      if (lm == 0) {
        int row = mi * 16 + lg * 4 + rg;
        sred_s[row][w] = ps[rg];
        sred_d[row][w] = pd[rg];
      }
    }
  }
  __syncthreads();
  if (t < 32) {
    int n = n0 + t;
    if (n < N) {
      a_src2[n] = sred_s[t][0] + sred_s[t][1] + sred_s[t][2] + sred_s[t][3];
      a_dst2[n] = sred_d[t][0] + sred_d[t][1] + sred_d[t][2] + sred_d[t][3];
    }
  }
}

// ---------------- Layer-2 aggregate -> out [N,128] ----------------
// 32-lane group per node; bf16 h2 gather (256B/edge), 4-deep pipelined edge loop.
__global__ __launch_bounds__(256) void k_agg2(
    const ushort_t* __restrict__ h2, const float* __restrict__ b2,
    const float* __restrict__ a_src2, const float* __restrict__ a_dst2,
    const int* __restrict__ offsets, const int* __restrict__ srclist,
    float* __restrict__ out, int N)
{
  int t = threadIdx.x, lane = t & 63;
  int g = lane >> 5, r = lane & 31;
  int n = blockIdx.x * 8 + (t >> 6) * 2 + g;
  if (n >= N) return;
  int off = offsets[n], deg = offsets[n + 1] - off;
  float adn = a_dst2[n];

  int c0 = min(deg, 32);
  int s_l = 0; float a_l = -1e30f;
  if (r < c0) { s_l = srclist[off + r]; a_l = lrelu(a_src2[s_l] + adn); }
  float m = a_l;
  for (int base = 32; base < deg; base += 32)    // rare
    if (r < deg - base) m = fmaxf(m, lrelu(a_src2[srclist[off + base + r]] + adn));
  #pragma unroll
  for (int msk = 16; msk > 0; msk >>= 1) m = fmaxf(m, __shfl_xor(m, msk, 32));

  float e_l = (r < c0) ? __expf(a_l - m) : 0.f;
  float den_p = e_l;
  float4 acc = {0.f, 0.f, 0.f, 0.f};

  int j = 0;
  for (; j + 4 <= c0; j += 4) {
    int   sA = __shfl(s_l, j, 32),     sB = __shfl(s_l, j + 1, 32);
    int   sC = __shfl(s_l, j + 2, 32), sD = __shfl(s_l, j + 3, 32);
    float eA = __shfl(e_l, j, 32),     eB = __shfl(e_l, j + 1, 32);
    float eC = __shfl(e_l, j + 2, 32), eD = __shfl(e_l, j + 3, 32);
    float4 hA = ld_h2q(h2, sA, r);
    float4 hB = ld_h2q(h2, sB, r);
    float4 hC = ld_h2q(h2, sC, r);
    float4 hD = ld_h2q(h2, sD, r);
    acc.x += eA * hA.x + eB * hB.x + eC * hC.x + eD * hD.x;
    acc.y += eA * hA.y + eB * hB.y + eC * hC.y + eD * hD.y;
    acc.z += eA * hA.z + eB * hB.z + eC * hC.z + eD * hD.z;
    acc.w += eA * hA.w + eB * hB.w + eC * hC.w + eD * hD.w;
  }
  for (; j < c0; ++j) {
    int sA = __shfl(s_l, j, 32);
    float eA = __shfl(e_l, j, 32);
    float4 hA = ld_h2q(h2, sA, r);
    acc.x += eA * hA.x; acc.y += eA * hA.y; acc.z += eA * hA.z; acc.w += eA * hA.w;
  }
  for (int base = 32; base < deg; base += 32) {  // rare
    int rem = min(32, deg - base);
    int sl2 = 0; float el2 = 0.f;
    if (r < rem) { sl2 = srclist[off + base + r]; el2 = __expf(lrelu(a_src2[sl2] + adn) - m); }
    den_p += el2;
    for (int q = 0; q < rem; ++q) {
      int s = __shfl(sl2, q, 32);
      float e = __shfl(el2, q, 32);
      float4 hv = ld_h2q(h2, s, r);
      acc.x += e * hv.x; acc.y += e * hv.y; acc.z += e * hv.z; acc.w += e * hv.w;
    }
  }
  #pragma unroll
  for (int msk = 16; msk > 0; msk >>= 1) den_p += __shfl_xor(den_p, msk, 32);
  float inv = 1.f / (den_p + 1e-16f);
  float4 bb = *(const float4*)&b2[r * 4];
  float4 o = {acc.x * inv + bb.x, acc.y * inv + bb.y, acc.z * inv + bb.z, acc.w * inv + bb.w};
  *(float4*)&out[(size_t)n * 128 + r * 4] = o;
}

extern "C" void kernel_launch(void* const* d_in, const int* in_sizes, int n_in,
                              void* d_out, int out_size, void* d_ws, size_t ws_size,
                              hipStream_t stream)
{
  const float* x        = (const float*)d_in[0];
  const int*   ei       = (const int*)d_in[1];
  const float* W1       = (const float*)d_in[2];
  const float* att_src1 = (const float*)d_in[3];
  const float* att_dst1 = (const float*)d_in[4];
  const float* b1       = (const float*)d_in[5];
  const float* W2       = (const float*)d_in[6];
  const float* att_src2 = (const float*)d_in[7];
  const float* att_dst2 = (const float*)d_in[8];
  const float* b2       = (const float*)d_in[9];
  float* out = (float*)d_out;

  int N = in_sizes[0] / 3;
  int E = in_sizes[1] / 2;

  char* p = (char*)d_ws;
  auto alloc = [&](size_t bytes) -> char* {
    char* r = p;
    p += (bytes + 255) & ~(size_t)255;
    return r;
  };
  float*    uv      = (float*)alloc(24 * 4);
  ushort_t* w2hi    = (ushort_t*)alloc(32768 * 2);
  ushort_t* w2lo    = (ushort_t*)alloc(32768 * 2);
  float4*   xp      = (float4*)alloc((size_t)N * 16);
  float*    a_src2  = (float*)alloc((size_t)N * 4);
  float*    a_dst2  = (float*)alloc((size_t)N * 4);
  int*      cnt     = (int*)alloc((size_t)N * 4);
  int*      incl    = (int*)alloc((size_t)N * 4);
  int*      csum    = (int*)alloc(64 * 4);
  int*      cbase   = (int*)alloc(64 * 4);
  int*      offsets = (int*)alloc((size_t)(N + 1) * 4);
  int*      cursor  = (int*)alloc((size_t)N * 4);
  int*      srclist = (int*)alloc((size_t)(E + N) * 4);
  float*    Xc      = (float*)alloc((size_t)16 * N * 4);
  ushort_t* h2      = (ushort_t*)alloc((size_t)128 * N * 2);

  int nch = (N + 1023) / 1024;

  hipMemsetAsync(cnt, 0, (size_t)N * 4, stream);
  k_prep<<<17, 256, 0, stream>>>(W1, att_src1, att_dst1, W2, w2hi, w2lo, uv);
  k_packx<<<(N + 255) / 256, 256, 0, stream>>>(x, xp, N);
  k_count<<<(E + 2047) / 2048, 256, 0, stream>>>(ei, E, cnt);
  k_scan1<<<nch, 1024, 0, stream>>>(cnt, N, incl, csum);
  k_scan2<<<1, 64, 0, stream>>>(csum, nch, cbase, offsets, N);
  k_scan3<<<nch, 1024, 0, stream>>>(cnt, incl, cbase, N, offsets, cursor, srclist);
  k_fill<<<(E + 2047) / 2048, 256, 0, stream>>>(ei, E, cursor, srclist);
  k_agg1<<<(N + 7) / 8, 256, 0, stream>>>(xp, uv, offsets, srclist, Xc, N);
  k_mm2<<<(N + 31) / 32, 256, 0, stream>>>(Xc, W1, b1, w2hi, w2lo, att_src2, att_dst2, h2, a_src2, a_dst2, N);
  k_agg2<<<(N + 7) / 8, 256, 0, stream>>>(h2, b2, a_src2, a_dst2, offsets, srclist, out, N);
}

// Round 12
// 208.894 us; speedup vs baseline: 2.1052x; 1.2580x over previous
//
#include <hip/hip_runtime.h>

#define NEG_SLOPE 0.2f
typedef unsigned short ushort_t;
typedef __attribute__((ext_vector_type(8))) short bf16x8;
typedef __attribute__((ext_vector_type(4))) float f32x4;

__device__ __forceinline__ float lrelu(float z){ return z > 0.f ? z : NEG_SLOPE * z; }

__device__ __forceinline__ ushort_t bf16_rn(float x){
  union { float f; unsigned u; } v; v.f = x;
  unsigned r = v.u + 0x7FFF + ((v.u >> 16) & 1);
  return (ushort_t)(r >> 16);
}
__device__ __forceinline__ float bf16_to_f(ushort_t h){
  union { unsigned u; float f; } v; v.u = ((unsigned)h) << 16;
  return v.f;
}

// load 4 consecutive bf16 channels of h2 row s at channel r*4, as float4
__device__ __forceinline__ float4 ld_h2q(const ushort_t* __restrict__ h2, int s, int r){
  uint2 u = *(const uint2*)&h2[(size_t)s * 128 + r * 4];
  float4 f;
  f.x = bf16_to_f((ushort_t)(u.x & 0xffffu));
  f.y = bf16_to_f((ushort_t)(u.x >> 16));
  f.z = bf16_to_f((ushort_t)(u.y & 0xffffu));
  f.w = bf16_to_f((ushort_t)(u.y >> 16));
  return f;
}

// ---------------- prep: pack W2 (bf16 hi/lo fragments) + u-vectors + packed x ----------------
__global__ __launch_bounds__(256) void k_prep(
    const float* __restrict__ W1, const float* __restrict__ att_src1, const float* __restrict__ att_dst1,
    const float* __restrict__ W2, const float* __restrict__ x,
    ushort_t* __restrict__ w2hi, ushort_t* __restrict__ w2lo,
    float* __restrict__ uv, float4* __restrict__ xp, int N)
{
  if (blockIdx.x >= 17) {            // packx part
    int n = (blockIdx.x - 17) * 256 + threadIdx.x;
    if (n < N) {
      float4 v = {x[n * 3], x[n * 3 + 1], x[n * 3 + 2], 0.f};
      xp[n] = v;
    }
    return;
  }
  int gid = blockIdx.x * 256 + threadIdx.x;
  if (gid < 4096) {
    int kc = gid >> 9, g = (gid >> 7) & 3, n = gid & 127;
    #pragma unroll
    for (int e = 0; e < 8; ++e) {
      int k = kc * 32 + g * 8 + e;
      float w = W2[k * 128 + n];
      ushort_t hi = bf16_rn(w);
      ushort_t lo = bf16_rn(w - bf16_to_f(hi));
      w2hi[(size_t)gid * 8 + e] = hi;
      w2lo[(size_t)gid * 8 + e] = lo;
    }
  } else if (gid < 4120) {
    int j = gid - 4096;              // 0..23 ; uv[k*4+h] = us, uv[12+k*4+h] = ud
    int jj = j % 12;
    int k = jj >> 2, h = jj & 3;
    const float* att = (j < 12) ? att_src1 : att_dst1;
    float s = 0.f;
    for (int c = 0; c < 64; ++c) s += W1[k * 256 + h * 64 + c] * att[h * 64 + c];
    uv[j] = s;
  }
}

// ---------------- bucketed CSR build (128 nodes per bucket, dst>>7) ----------------
// pass 1: coarse histogram, LDS pre-aggregated -> ~NB atomics per block
__global__ __launch_bounds__(256) void k_hist(
    const int* __restrict__ ei, int E, int NB, int* __restrict__ hist)
{
  __shared__ int h[512];
  int t = threadIdx.x;
  for (int i = t; i < NB; i += 256) h[i] = 0;
  __syncthreads();
  int e0 = (blockIdx.x * 256 + t) * 8;
  #pragma unroll
  for (int k = 0; k < 8; ++k) {
    int e = e0 + k;
    if (e < E) atomicAdd(&h[ei[E + e] >> 7], 1);
  }
  __syncthreads();
  for (int i = t; i < NB; i += 256)
    if (h[i]) atomicAdd(&hist[i], h[i]);
}

// pass 2: scan bucket totals (single block; NB <= 512)
__global__ __launch_bounds__(512) void k_scanB(
    const int* __restrict__ hist, int NB, int E,
    int* __restrict__ cbase, int* __restrict__ cursorB)
{
  __shared__ int s[512];
  int t = threadIdx.x;
  int v = (t < NB) ? hist[t] : 0;
  s[t] = v;
  __syncthreads();
  for (int off = 1; off < 512; off <<= 1) {
    int u = (t >= off) ? s[t - off] : 0;
    __syncthreads();
    s[t] += u;
    __syncthreads();
  }
  if (t < NB) {
    int excl = s[t] - v;
    cbase[t] = excl;
    cursorB[t] = excl;
  }
  if (t == NB - 1) cbase[NB] = s[t];   // == E
}

// pass 3: scatter (src,dst) pairs into bucket regions; LDS ranking, 1 far-atomic per (block,bucket)
__global__ __launch_bounds__(256) void k_scatter(
    const int* __restrict__ ei, int E, int NB,
    int* __restrict__ cursorB, uint2* __restrict__ pairs)
{
  __shared__ int lcnt[512];
  __shared__ int gb[512];
  int t = threadIdx.x;
  for (int i = t; i < NB; i += 256) lcnt[i] = 0;
  __syncthreads();
  int e0 = (blockIdx.x * 256 + t) * 8;
  int lrank[8], dst[8], src[8];
  #pragma unroll
  for (int k = 0; k < 8; ++k) {
    int e = e0 + k;
    if (e < E) {
      src[k] = ei[e];
      dst[k] = ei[E + e];
      lrank[k] = atomicAdd(&lcnt[dst[k] >> 7], 1);
    }
  }
  __syncthreads();
  for (int i = t; i < NB; i += 256)
    gb[i] = lcnt[i] ? atomicAdd(&cursorB[i], lcnt[i]) : 0;
  __syncthreads();
  #pragma unroll
  for (int k = 0; k < 8; ++k) {
    int e = e0 + k;
    if (e < E) {
      uint2 pr; pr.x = (unsigned)src[k]; pr.y = (unsigned)dst[k];
      pairs[gb[dst[k] >> 7] + lrank[k]] = pr;
    }
  }
}

// pass 4: per-bucket local count -> scan(+1 self-loop) -> offsets + srclist. No global atomics.
__global__ __launch_bounds__(256) void k_bucket(
    const uint2* __restrict__ pairs, const int* __restrict__ cbase,
    int N, int NB, int E,
    int* __restrict__ offsets, int* __restrict__ srclist)
{
  __shared__ int lc[128];
  __shared__ int lexcl[128];
  __shared__ int lcur[128];
  __shared__ int s[256];
  int b = blockIdx.x;
  int t = threadIdx.x;
  int n0 = b << 7;
  int nloc = min(128, N - n0);
  int ebeg = cbase[b], eend = cbase[b + 1];
  int Gb = ebeg + n0;                      // global base: edges before + self-loops before

  if (t < 128) lc[t] = 0;
  __syncthreads();
  for (int e = ebeg + t; e < eend; e += 256)
    atomicAdd(&lc[pairs[e].y & 127], 1);
  __syncthreads();

  int v = (t < nloc) ? lc[t] + 1 : 0;      // +1 self-loop per node
  s[t] = v;
  __syncthreads();
  for (int off = 1; off < 256; off <<= 1) {
    int u = (t >= off) ? s[t - off] : 0;
    __syncthreads();
    s[t] += u;
    __syncthreads();
  }
  if (t < nloc) {
    int excl = s[t] - v;
    lexcl[t] = excl;
    lcur[t] = excl;
    offsets[n0 + t] = Gb + excl;
  }
  __syncthreads();

  for (int e = ebeg + t; e < eend; e += 256) {
    uint2 pr = pairs[e];
    int i = pr.y & 127;
    int pos = atomicAdd(&lcur[i], 1);
    srclist[Gb + pos] = (int)pr.x;
  }
  if (t < nloc) srclist[Gb + lexcl[t] + lc[t]] = n0 + t;  // self-loop last in segment
  if (b == NB - 1 && t == 0) offsets[N] = E + N;
}

// ---------------- Layer-1 aggregate -> X[N,16] = {den[4], xa0[4], xa1[4], xa2[4]} ----------------
__global__ __launch_bounds__(256) void k_agg1(
    const float4* __restrict__ xp, const float* __restrict__ uv,
    const int* __restrict__ offsets, const int* __restrict__ srclist,
    float* __restrict__ X, int N)
{
  int t = threadIdx.x;
  int lane = t & 63;
  int g = lane >> 5, r = lane & 31;
  int n = blockIdx.x * 8 + (t >> 6) * 2 + g;
  if (n >= N) return;

  float us[12], ud[12];
  #pragma unroll
  for (int j = 0; j < 12; ++j) { us[j] = uv[j]; ud[j] = uv[12 + j]; }

  float4 xn = xp[n];
  float ad0 = xn.x * ud[0] + xn.y * ud[4] + xn.z * ud[8];
  float ad1 = xn.x * ud[1] + xn.y * ud[5] + xn.z * ud[9];
  float ad2 = xn.x * ud[2] + xn.y * ud[6] + xn.z * ud[10];
  float ad3 = xn.x * ud[3] + xn.y * ud[7] + xn.z * ud[11];

  int off = offsets[n];
  int deg = offsets[n + 1] - off;
  int c0 = min(deg, 32);
  float a0 = -1e30f, a1 = -1e30f, a2 = -1e30f, a3 = -1e30f;
  float x0 = 0.f, x1 = 0.f, x2 = 0.f;
  if (r < c0) {
    int s = srclist[off + r];
    float4 xs = xp[s];
    x0 = xs.x; x1 = xs.y; x2 = xs.z;
    a0 = lrelu(x0 * us[0] + x1 * us[4] + x2 * us[8]  + ad0);
    a1 = lrelu(x0 * us[1] + x1 * us[5] + x2 * us[9]  + ad1);
    a2 = lrelu(x0 * us[2] + x1 * us[6] + x2 * us[10] + ad2);
    a3 = lrelu(x0 * us[3] + x1 * us[7] + x2 * us[11] + ad3);
  }
  float m0 = a0, m1 = a1, m2 = a2, m3 = a3;
  for (int base = 32; base < deg; base += 32) {   // rare: deg>32
    if (r < deg - base) {
      int s = srclist[off + base + r];
      float4 xs = xp[s];
      m0 = fmaxf(m0, lrelu(xs.x * us[0] + xs.y * us[4] + xs.z * us[8]  + ad0));
      m1 = fmaxf(m1, lrelu(xs.x * us[1] + xs.y * us[5] + xs.z * us[9]  + ad1));
      m2 = fmaxf(m2, lrelu(xs.x * us[2] + xs.y * us[6] + xs.z * us[10] + ad2));
      m3 = fmaxf(m3, lrelu(xs.x * us[3] + xs.y * us[7] + xs.z * us[11] + ad3));
    }
  }
  #pragma unroll
  for (int msk = 16; msk > 0; msk >>= 1) {
    m0 = fmaxf(m0, __shfl_xor(m0, msk, 32)); m1 = fmaxf(m1, __shfl_xor(m1, msk, 32));
    m2 = fmaxf(m2, __shfl_xor(m2, msk, 32)); m3 = fmaxf(m3, __shfl_xor(m3, msk, 32));
  }

  float e0 = (r < c0) ? __expf(a0 - m0) : 0.f;
  float e1 = (r < c0) ? __expf(a1 - m1) : 0.f;
  float e2 = (r < c0) ? __expf(a2 - m2) : 0.f;
  float e3 = (r < c0) ? __expf(a3 - m3) : 0.f;
  float d0 = e0, d1 = e1, d2 = e2, d3 = e3;
  float xa00 = e0 * x0, xa01 = e1 * x0, xa02 = e2 * x0, xa03 = e3 * x0;
  float xa10 = e0 * x1, xa11 = e1 * x1, xa12 = e2 * x1, xa13 = e3 * x1;
  float xa20 = e0 * x2, xa21 = e1 * x2, xa22 = e2 * x2, xa23 = e3 * x2;

  for (int base = 32; base < deg; base += 32) {   // rare
    if (r < deg - base) {
      int s = srclist[off + base + r];
      float4 xs = xp[s];
      float ee0 = __expf(lrelu(xs.x * us[0] + xs.y * us[4] + xs.z * us[8]  + ad0) - m0);
      float ee1 = __expf(lrelu(xs.x * us[1] + xs.y * us[5] + xs.z * us[9]  + ad1) - m1);
      float ee2 = __expf(lrelu(xs.x * us[2] + xs.y * us[6] + xs.z * us[10] + ad2) - m2);
      float ee3 = __expf(lrelu(xs.x * us[3] + xs.y * us[7] + xs.z * us[11] + ad3) - m3);
      d0 += ee0; d1 += ee1; d2 += ee2; d3 += ee3;
      xa00 += ee0 * xs.x; xa01 += ee1 * xs.x; xa02 += ee2 * xs.x; xa03 += ee3 * xs.x;
      xa10 += ee0 * xs.y; xa11 += ee1 * xs.y; xa12 += ee2 * xs.y; xa13 += ee3 * xs.y;
      xa20 += ee0 * xs.z; xa21 += ee1 * xs.z; xa22 += ee2 * xs.z; xa23 += ee3 * xs.z;
    }
  }

  #pragma unroll
  for (int msk = 16; msk > 0; msk >>= 1) {
    d0 += __shfl_xor(d0, msk, 32); d1 += __shfl_xor(d1, msk, 32);
    d2 += __shfl_xor(d2, msk, 32); d3 += __shfl_xor(d3, msk, 32);
    xa00 += __shfl_xor(xa00, msk, 32); xa01 += __shfl_xor(xa01, msk, 32);
    xa02 += __shfl_xor(xa02, msk, 32); xa03 += __shfl_xor(xa03, msk, 32);
    xa10 += __shfl_xor(xa10, msk, 32); xa11 += __shfl_xor(xa11, msk, 32);
    xa12 += __shfl_xor(xa12, msk, 32); xa13 += __shfl_xor(xa13, msk, 32);
    xa20 += __shfl_xor(xa20, msk, 32); xa21 += __shfl_xor(xa21, msk, 32);
    xa22 += __shfl_xor(xa22, msk, 32); xa23 += __shfl_xor(xa23, msk, 32);
  }

  if (r < 16) {
    int j = r;
    float v =
      j == 0 ? d0 : j == 1 ? d1 : j == 2 ? d2 : j == 3 ? d3 :
      j == 4 ? xa00 : j == 5 ? xa01 : j == 6 ? xa02 : j == 7 ? xa03 :
      j == 8 ? xa10 : j == 9 ? xa11 : j == 10 ? xa12 : j == 11 ? xa13 :
      j == 12 ? xa20 : j == 13 ? xa21 : j == 14 ? xa22 : xa23;
    X[(size_t)n * 16 + j] = v;
  }
}

// ---------------- Fused expand + split-bf16 MFMA GEMM + layer-2 scores ----------------
__global__ __launch_bounds__(256) void k_mm2(
    const float* __restrict__ Xc, const float* __restrict__ W1, const float* __restrict__ b1,
    const ushort_t* __restrict__ w2hi, const ushort_t* __restrict__ w2lo,
    const float* __restrict__ att_src2, const float* __restrict__ att_dst2,
    ushort_t* __restrict__ h2, float* __restrict__ a_src2, float* __restrict__ a_dst2, int N)
{
  __shared__ ushort_t h1hi[32 * 256];
  __shared__ ushort_t h1lo[32 * 256];
  __shared__ float Xs[512];
  __shared__ float W1s[768];
  __shared__ float b1s[256];
  __shared__ float invs[128];
  __shared__ float sred_s[32][4];
  __shared__ float sred_d[32][4];

  int t = threadIdx.x;
  int n0 = blockIdx.x * 32;

  for (int i = t; i < 768; i += 256) W1s[i] = W1[i];
  b1s[t] = b1[t];
  for (int i = t; i < 512; i += 256) {
    int idx = n0 * 16 + i;
    Xs[i] = (idx < N * 16) ? Xc[idx] : 0.f;
  }
  __syncthreads();
  if (t < 128) invs[t] = 1.f / (Xs[(t >> 2) * 16 + (t & 3)] + 1e-16f);
  __syncthreads();

  {
    int c = t, h = t >> 6;
    float w0 = W1s[c], w1 = W1s[256 + c], w2v = W1s[512 + c], bb = b1s[c];
    #pragma unroll 4
    for (int i = 0; i < 32; ++i) {
      float inv = invs[i * 4 + h];
      float X0 = Xs[i * 16 + 4 + h] * inv;
      float X1 = Xs[i * 16 + 8 + h] * inv;
      float X2 = Xs[i * 16 + 12 + h] * inv;
      float v = fmaf(w0, X0, fmaf(w1, X1, fmaf(w2v, X2, bb)));
      v = v > 0.f ? v : __expf(v) - 1.f;      // ELU
      ushort_t hi = bf16_rn(v);
      ushort_t lo = bf16_rn(v - bf16_to_f(hi));
      int idx = (i * 256 + c) ^ ((i & 7) << 3);   // T2 XOR swizzle (ushort units)
      h1hi[idx] = hi;
      h1lo[idx] = lo;
    }
  }
  __syncthreads();

  int lane = t & 63;
  int w = t >> 6;
  int lm = lane & 15, lg = lane >> 4;

  f32x4 acc[2][2];
  f32x4 zz = {0.f, 0.f, 0.f, 0.f};
  acc[0][0] = zz; acc[0][1] = zz; acc[1][0] = zz; acc[1][1] = zz;

  int rowA0 = lm, rowA1 = 16 + lm;
  int swz0 = (rowA0 & 7) << 3, swz1 = (rowA1 & 7) << 3;

  for (int kc = 0; kc < 8; ++kc) {
    int ks = kc * 32 + lg * 8;
    int ia0 = (rowA0 * 256 + ks) ^ swz0;
    int ia1 = (rowA1 * 256 + ks) ^ swz1;
    bf16x8 ah0 = *(const bf16x8*)&h1hi[ia0];
    bf16x8 al0 = *(const bf16x8*)&h1lo[ia0];
    bf16x8 ah1 = *(const bf16x8*)&h1hi[ia1];
    bf16x8 al1 = *(const bf16x8*)&h1lo[ia1];
    size_t bb0 = ((size_t)((kc * 4 + lg) * 128) + (w * 32 + lm)) * 8;
    size_t bb1 = bb0 + 16 * 8;
    bf16x8 bh0 = *(const bf16x8*)&w2hi[bb0];
    bf16x8 bl0 = *(const bf16x8*)&w2lo[bb0];
    bf16x8 bh1 = *(const bf16x8*)&w2hi[bb1];
    bf16x8 bl1 = *(const bf16x8*)&w2lo[bb1];

    acc[0][0] = __builtin_amdgcn_mfma_f32_16x16x32_bf16(ah0, bh0, acc[0][0], 0, 0, 0);
    acc[0][1] = __builtin_amdgcn_mfma_f32_16x16x32_bf16(ah0, bh1, acc[0][1], 0, 0, 0);
    acc[1][0] = __builtin_amdgcn_mfma_f32_16x16x32_bf16(ah1, bh0, acc[1][0], 0, 0, 0);
    acc[1][1] = __builtin_amdgcn_mfma_f32_16x16x32_bf16(ah1, bh1, acc[1][1], 0, 0, 0);
    acc[0][0] = __builtin_amdgcn_mfma_f32_16x16x32_bf16(ah0, bl0, acc[0][0], 0, 0, 0);
    acc[0][1] = __builtin_amdgcn_mfma_f32_16x16x32_bf16(ah0, bl1, acc[0][1], 0, 0, 0);
    acc[1][0] = __builtin_amdgcn_mfma_f32_16x16x32_bf16(ah1, bl0, acc[1][0], 0, 0, 0);
    acc[1][1] = __builtin_amdgcn_mfma_f32_16x16x32_bf16(ah1, bl1, acc[1][1], 0, 0, 0);
    acc[0][0] = __builtin_amdgcn_mfma_f32_16x16x32_bf16(al0, bh0, acc[0][0], 0, 0, 0);
    acc[0][1] = __builtin_amdgcn_mfma_f32_16x16x32_bf16(al0, bh1, acc[0][1], 0, 0, 0);
    acc[1][0] = __builtin_amdgcn_mfma_f32_16x16x32_bf16(al1, bh0, acc[1][0], 0, 0, 0);
    acc[1][1] = __builtin_amdgcn_mfma_f32_16x16x32_bf16(al1, bh1, acc[1][1], 0, 0, 0);
  }

  // epilogue: C layout col=lane&15, row=(lane>>4)*4+reg  [verified m89/m91]
  float as0 = att_src2[w * 32 + lm], as1 = att_src2[w * 32 + 16 + lm];
  float ad0 = att_dst2[w * 32 + lm], ad1 = att_dst2[w * 32 + 16 + lm];
  #pragma unroll
  for (int mi = 0; mi < 2; ++mi) {
    float ps[4], pd[4];
    #pragma unroll
    for (int rg = 0; rg < 4; ++rg) {
      float c0v = acc[mi][0][rg], c1v = acc[mi][1][rg];
      int nrow = n0 + mi * 16 + lg * 4 + rg;
      if (nrow < N) {
        h2[(size_t)nrow * 128 + w * 32 + lm] = bf16_rn(c0v);
        h2[(size_t)nrow * 128 + w * 32 + 16 + lm] = bf16_rn(c1v);
      }
      ps[rg] = c0v * as0 + c1v * as1;
      pd[rg] = c0v * ad0 + c1v * ad1;
    }
    #pragma unroll
    for (int rg = 0; rg < 4; ++rg) {
      #pragma unroll
      for (int m = 8; m >= 1; m >>= 1) {
        ps[rg] += __shfl_xor(ps[rg], m, 64);
        pd[rg] += __shfl_xor(pd[rg], m, 64);
      }
      if (lm == 0) {
        int row = mi * 16 + lg * 4 + rg;
        sred_s[row][w] = ps[rg];
        sred_d[row][w] = pd[rg];
      }
    }
  }
  __syncthreads();
  if (t < 32) {
    int n = n0 + t;
    if (n < N) {
      a_src2[n] = sred_s[t][0] + sred_s[t][1] + sred_s[t][2] + sred_s[t][3];
      a_dst2[n] = sred_d[t][0] + sred_d[t][1] + sred_d[t][2] + sred_d[t][3];
    }
  }
}

// ---------------- Layer-2 aggregate -> out [N,128] ----------------
__global__ __launch_bounds__(256) void k_agg2(
    const ushort_t* __restrict__ h2, const float* __restrict__ b2,
    const float* __restrict__ a_src2, const float* __restrict__ a_dst2,
    const int* __restrict__ offsets, const int* __restrict__ srclist,
    float* __restrict__ out, int N)
{
  int t = threadIdx.x, lane = t & 63;
  int g = lane >> 5, r = lane & 31;
  int n = blockIdx.x * 8 + (t >> 6) * 2 + g;
  if (n >= N) return;
  int off = offsets[n], deg = offsets[n + 1] - off;
  float adn = a_dst2[n];

  int c0 = min(deg, 32);
  int s_l = 0; float a_l = -1e30f;
  if (r < c0) { s_l = srclist[off + r]; a_l = lrelu(a_src2[s_l] + adn); }
  float m = a_l;
  for (int base = 32; base < deg; base += 32)    // rare
    if (r < deg - base) m = fmaxf(m, lrelu(a_src2[srclist[off + base + r]] + adn));
  #pragma unroll
  for (int msk = 16; msk > 0; msk >>= 1) m = fmaxf(m, __shfl_xor(m, msk, 32));

  float e_l = (r < c0) ? __expf(a_l - m) : 0.f;
  float den_p = e_l;
  float4 acc = {0.f, 0.f, 0.f, 0.f};

  int j = 0;
  for (; j + 4 <= c0; j += 4) {
    int   sA = __shfl(s_l, j, 32),     sB = __shfl(s_l, j + 1, 32);
    int   sC = __shfl(s_l, j + 2, 32), sD = __shfl(s_l, j + 3, 32);
    float eA = __shfl(e_l, j, 32),     eB = __shfl(e_l, j + 1, 32);
    float eC = __shfl(e_l, j + 2, 32), eD = __shfl(e_l, j + 3, 32);
    float4 hA = ld_h2q(h2, sA, r);
    float4 hB = ld_h2q(h2, sB, r);
    float4 hC = ld_h2q(h2, sC, r);
    float4 hD = ld_h2q(h2, sD, r);
    acc.x += eA * hA.x + eB * hB.x + eC * hC.x + eD * hD.x;
    acc.y += eA * hA.y + eB * hB.y + eC * hC.y + eD * hD.y;
    acc.z += eA * hA.z + eB * hB.z + eC * hC.z + eD * hD.z;
    acc.w += eA * hA.w + eB * hB.w + eC * hC.w + eD * hD.w;
  }
  for (; j < c0; ++j) {
    int sA = __shfl(s_l, j, 32);
    float eA = __shfl(e_l, j, 32);
    float4 hA = ld_h2q(h2, sA, r);
    acc.x += eA * hA.x; acc.y += eA * hA.y; acc.z += eA * hA.z; acc.w += eA * hA.w;
  }
  for (int base = 32; base < deg; base += 32) {  // rare
    int rem = min(32, deg - base);
    int sl2 = 0; float el2 = 0.f;
    if (r < rem) { sl2 = srclist[off + base + r]; el2 = __expf(lrelu(a_src2[sl2] + adn) - m); }
    den_p += el2;
    for (int q = 0; q < rem; ++q) {
      int s = __shfl(sl2, q, 32);
      float e = __shfl(el2, q, 32);
      float4 hv = ld_h2q(h2, s, r);
      acc.x += e * hv.x; acc.y += e * hv.y; acc.z += e * hv.z; acc.w += e * hv.w;
    }
  }
  #pragma unroll
  for (int msk = 16; msk > 0; msk >>= 1) den_p += __shfl_xor(den_p, msk, 32);
  float inv = 1.f / (den_p + 1e-16f);
  float4 bb = *(const float4*)&b2[r * 4];
  float4 o = {acc.x * inv + bb.x, acc.y * inv + bb.y, acc.z * inv + bb.z, acc.w * inv + bb.w};
  *(float4*)&out[(size_t)n * 128 + r * 4] = o;
}

extern "C" void kernel_launch(void* const* d_in, const int* in_sizes, int n_in,
                              void* d_out, int out_size, void* d_ws, size_t ws_size,
                              hipStream_t stream)
{
  const float* x        = (const float*)d_in[0];
  const int*   ei       = (const int*)d_in[1];
  const float* W1       = (const float*)d_in[2];
  const float* att_src1 = (const float*)d_in[3];
  const float* att_dst1 = (const float*)d_in[4];
  const float* b1       = (const float*)d_in[5];
  const float* W2       = (const float*)d_in[6];
  const float* att_src2 = (const float*)d_in[7];
  const float* att_dst2 = (const float*)d_in[8];
  const float* b2       = (const float*)d_in[9];
  float* out = (float*)d_out;

  int N = in_sizes[0] / 3;
  int E = in_sizes[1] / 2;
  int NB = (N + 127) >> 7;     // 128 nodes per bucket; NB <= 512 for N <= 65536

  char* p = (char*)d_ws;
  auto alloc = [&](size_t bytes) -> char* {
    char* r = p;
    p += (bytes + 255) & ~(size_t)255;
    return r;
  };
  float*    uv      = (float*)alloc(24 * 4);
  ushort_t* w2hi    = (ushort_t*)alloc(32768 * 2);
  ushort_t* w2lo    = (ushort_t*)alloc(32768 * 2);
  float4*   xp      = (float4*)alloc((size_t)N * 16);
  float*    a_src2  = (float*)alloc((size_t)N * 4);
  float*    a_dst2  = (float*)alloc((size_t)N * 4);
  int*      hist    = (int*)alloc(512 * 4);
  int*      cbase   = (int*)alloc(513 * 4);
  int*      cursorB = (int*)alloc(512 * 4);
  uint2*    pairs   = (uint2*)alloc((size_t)E * 8);
  int*      offsets = (int*)alloc((size_t)(N + 1) * 4);
  int*      srclist = (int*)alloc((size_t)(E + N) * 4);
  float*    Xc      = (float*)alloc((size_t)16 * N * 4);
  ushort_t* h2      = (ushort_t*)alloc((size_t)128 * N * 2);

  int nEB = (E + 2047) / 2048;

  hipMemsetAsync(hist, 0, 512 * 4, stream);
  k_prep<<<17 + (N + 255) / 256, 256, 0, stream>>>(W1, att_src1, att_dst1, W2, x, w2hi, w2lo, uv, xp, N);
  k_hist<<<nEB, 256, 0, stream>>>(ei, E, NB, hist);
  k_scanB<<<1, 512, 0, stream>>>(hist, NB, E, cbase, cursorB);
  k_scatter<<<nEB, 256, 0, stream>>>(ei, E, NB, cursorB, pairs);
  k_bucket<<<NB, 256, 0, stream>>>(pairs, cbase, N, NB, E, offsets, srclist);
  k_agg1<<<(N + 7) / 8, 256, 0, stream>>>(xp, uv, offsets, srclist, Xc, N);
  k_mm2<<<(N + 31) / 32, 256, 0, stream>>>(Xc, W1, b1, w2hi, w2lo, att_src2, att_dst2, h2, a_src2, a_dst2, N);
  k_agg2<<<(N + 7) / 8, 256, 0, stream>>>(h2, b2, a_src2, a_dst2, offsets, srclist, out, N);
}

// Round 14
// 205.037 us; speedup vs baseline: 2.1448x; 1.0188x over previous
//
#include <hip/hip_runtime.h>

#define NEG_SLOPE 0.2f
typedef unsigned short ushort_t;
typedef __attribute__((ext_vector_type(8))) short bf16x8;
typedef __attribute__((ext_vector_type(4))) float f32x4;

__device__ __forceinline__ float lrelu(float z){ return z > 0.f ? z : NEG_SLOPE * z; }

__device__ __forceinline__ ushort_t bf16_rn(float x){
  union { float f; unsigned u; } v; v.f = x;
  unsigned r = v.u + 0x7FFF + ((v.u >> 16) & 1);
  return (ushort_t)(r >> 16);
}
__device__ __forceinline__ float bf16_to_f(ushort_t h){
  union { unsigned u; float f; } v; v.u = ((unsigned)h) << 16;
  return v.f;
}

// load 4 consecutive bf16 channels of h2 row s at channel r*4, as float4
__device__ __forceinline__ float4 ld_h2q(const ushort_t* __restrict__ h2, int s, int r){
  uint2 u = *(const uint2*)&h2[(size_t)s * 128 + r * 4];
  float4 f;
  f.x = bf16_to_f((ushort_t)(u.x & 0xffffu));
  f.y = bf16_to_f((ushort_t)(u.x >> 16));
  f.z = bf16_to_f((ushort_t)(u.y & 0xffffu));
  f.w = bf16_to_f((ushort_t)(u.y >> 16));
  return f;
}

// ---------------- fused prep: W2 pack + u-vectors + packed x + coarse histogram ----------------
__global__ __launch_bounds__(256) void k_prep(
    const float* __restrict__ W1, const float* __restrict__ att_src1, const float* __restrict__ att_dst1,
    const float* __restrict__ W2, const float* __restrict__ x,
    const int* __restrict__ ei, int E, int NB, int NPX,
    ushort_t* __restrict__ w2hi, ushort_t* __restrict__ w2lo,
    float* __restrict__ uv, float4* __restrict__ xp, int* __restrict__ hist, int N)
{
  __shared__ int h[512];
  int b = blockIdx.x;
  int t = threadIdx.x;
  if (b < 17) {                      // W2 pack + uv
    int gid = b * 256 + t;
    if (gid < 4096) {
      int kc = gid >> 9, g = (gid >> 7) & 3, n = gid & 127;
      #pragma unroll
      for (int e = 0; e < 8; ++e) {
        int k = kc * 32 + g * 8 + e;
        float w = W2[k * 128 + n];
        ushort_t hi = bf16_rn(w);
        ushort_t lo = bf16_rn(w - bf16_to_f(hi));
        w2hi[(size_t)gid * 8 + e] = hi;
        w2lo[(size_t)gid * 8 + e] = lo;
      }
    } else if (gid < 4120) {
      int j = gid - 4096;            // 0..23 ; uv[k*4+h] = us, uv[12+k*4+h] = ud
      int jj = j % 12;
      int k = jj >> 2, hh = jj & 3;
      const float* att = (j < 12) ? att_src1 : att_dst1;
      float s = 0.f;
      for (int c = 0; c < 64; ++c) s += W1[k * 256 + hh * 64 + c] * att[hh * 64 + c];
      uv[j] = s;
    }
    return;
  }
  if (b < 17 + NPX) {                // packx
    int n = (b - 17) * 256 + t;
    if (n < N) {
      float4 v = {x[n * 3], x[n * 3 + 1], x[n * 3 + 2], 0.f};
      xp[n] = v;
    }
    return;
  }
  // histogram part (branch uniform per block; barriers fine)
  for (int i = t; i < NB; i += 256) h[i] = 0;
  __syncthreads();
  int e0 = ((b - 17 - NPX) * 256 + t) * 8;
  #pragma unroll
  for (int k = 0; k < 8; ++k) {
    int e = e0 + k;
    if (e < E) atomicAdd(&h[ei[E + e] >> 7], 1);
  }
  __syncthreads();
  for (int i = t; i < NB; i += 256)
    if (h[i]) atomicAdd(&hist[i], h[i]);
}

// ---------------- bucketed CSR build (128 nodes per bucket, dst>>7) ----------------
// pass 2: scan bucket totals (single block; NB <= 512)
__global__ __launch_bounds__(512) void k_scanB(
    const int* __restrict__ hist, int NB, int E,
    int* __restrict__ cbase, int* __restrict__ cursorB)
{
  __shared__ int s[512];
  int t = threadIdx.x;
  int v = (t < NB) ? hist[t] : 0;
  s[t] = v;
  __syncthreads();
  for (int off = 1; off < 512; off <<= 1) {
    int u = (t >= off) ? s[t - off] : 0;
    __syncthreads();
    s[t] += u;
    __syncthreads();
  }
  if (t < NB) {
    int excl = s[t] - v;
    cbase[t] = excl;
    cursorB[t] = excl;
  }
  if (t == NB - 1) cbase[NB] = s[t];   // == E
}

// pass 3: scatter packed (src<<7)|(dst&127) into bucket regions; LDS ranking.
// Barriers are UNCONDITIONAL straight-line code; only loads/stores are predicated.
__global__ __launch_bounds__(256) void k_scatter(
    const int* __restrict__ ei, int E, int NB,
    int* __restrict__ cursorB, unsigned* __restrict__ pairs)
{
  __shared__ int lcnt[512];
  __shared__ int gb[512];
  int t = threadIdx.x;
  for (int i = t; i < NB; i += 256) lcnt[i] = 0;
  __syncthreads();

  int e0 = (blockIdx.x * 256 + t) * 8;
  int lrank[8], dst[8], src[8];
  if (e0 + 8 <= E) {                 // per-thread predicate, no barrier inside
    int4 s0 = *(const int4*)&ei[e0];
    int4 s1 = *(const int4*)&ei[e0 + 4];
    int4 d0 = *(const int4*)&ei[E + e0];
    int4 d1 = *(const int4*)&ei[E + e0 + 4];
    src[0]=s0.x; src[1]=s0.y; src[2]=s0.z; src[3]=s0.w;
    src[4]=s1.x; src[5]=s1.y; src[6]=s1.z; src[7]=s1.w;
    dst[0]=d0.x; dst[1]=d0.y; dst[2]=d0.z; dst[3]=d0.w;
    dst[4]=d1.x; dst[5]=d1.y; dst[6]=d1.z; dst[7]=d1.w;
  } else {
    #pragma unroll
    for (int k = 0; k < 8; ++k) {
      int e = e0 + k;
      src[k] = (e < E) ? ei[e] : 0;
      dst[k] = (e < E) ? ei[E + e] : 0;
    }
  }
  #pragma unroll
  for (int k = 0; k < 8; ++k)
    if (e0 + k < E) lrank[k] = atomicAdd(&lcnt[dst[k] >> 7], 1);

  __syncthreads();
  for (int i = t; i < NB; i += 256)
    gb[i] = lcnt[i] ? atomicAdd(&cursorB[i], lcnt[i]) : 0;
  __syncthreads();

  #pragma unroll
  for (int k = 0; k < 8; ++k)
    if (e0 + k < E)
      pairs[gb[dst[k] >> 7] + lrank[k]] = ((unsigned)src[k] << 7) | (unsigned)(dst[k] & 127);
}

// pass 4: per-bucket local count -> scan(+1 self-loop) -> offsets + srclist. No global atomics.
__global__ __launch_bounds__(256) void k_bucket(
    const unsigned* __restrict__ pairs, const int* __restrict__ cbase,
    int N, int NB, int E,
    int* __restrict__ offsets, int* __restrict__ srclist)
{
  __shared__ int lc[128];
  __shared__ int lexcl[128];
  __shared__ int lcur[128];
  __shared__ int s[256];
  int b = blockIdx.x;
  int t = threadIdx.x;
  int n0 = b << 7;
  int nloc = min(128, N - n0);
  int ebeg = cbase[b], eend = cbase[b + 1];
  int Gb = ebeg + n0;                      // global base: edges before + self-loops before

  if (t < 128) lc[t] = 0;
  __syncthreads();
  for (int e = ebeg + t; e < eend; e += 256)
    atomicAdd(&lc[pairs[e] & 127], 1);
  __syncthreads();

  int v = (t < nloc) ? lc[t] + 1 : 0;      // +1 self-loop per node
  s[t] = v;
  __syncthreads();
  for (int off = 1; off < 256; off <<= 1) {
    int u = (t >= off) ? s[t - off] : 0;
    __syncthreads();
    s[t] += u;
    __syncthreads();
  }
  if (t < nloc) {
    int excl = s[t] - v;
    lexcl[t] = excl;
    lcur[t] = excl;
    offsets[n0 + t] = Gb + excl;
  }
  __syncthreads();

  for (int e = ebeg + t; e < eend; e += 256) {
    unsigned pr = pairs[e];
    int i = (int)(pr & 127u);
    int pos = atomicAdd(&lcur[i], 1);
    srclist[Gb + pos] = (int)(pr >> 7);
  }
  if (t < nloc) srclist[Gb + lexcl[t] + lc[t]] = n0 + t;  // self-loop last in segment
  if (b == NB - 1 && t == 0) offsets[N] = E + N;
}

// ---------------- Layer-1 aggregate -> X[N,16] = {den[4], xa0[4], xa1[4], xa2[4]} ----------------
__global__ __launch_bounds__(256) void k_agg1(
    const float4* __restrict__ xp, const float* __restrict__ uv,
    const int* __restrict__ offsets, const int* __restrict__ srclist,
    float* __restrict__ X, int N)
{
  int t = threadIdx.x;
  int lane = t & 63;
  int g = lane >> 5, r = lane & 31;
  int n = blockIdx.x * 8 + (t >> 6) * 2 + g;
  if (n >= N) return;

  float us[12], ud[12];
  #pragma unroll
  for (int j = 0; j < 12; ++j) { us[j] = uv[j]; ud[j] = uv[12 + j]; }

  float4 xn = xp[n];
  float ad0 = xn.x * ud[0] + xn.y * ud[4] + xn.z * ud[8];
  float ad1 = xn.x * ud[1] + xn.y * ud[5] + xn.z * ud[9];
  float ad2 = xn.x * ud[2] + xn.y * ud[6] + xn.z * ud[10];
  float ad3 = xn.x * ud[3] + xn.y * ud[7] + xn.z * ud[11];

  int off = offsets[n];
  int deg = offsets[n + 1] - off;
  int c0 = min(deg, 32);
  float a0 = -1e30f, a1 = -1e30f, a2 = -1e30f, a3 = -1e30f;
  float x0 = 0.f, x1 = 0.f, x2 = 0.f;
  if (r < c0) {
    int s = srclist[off + r];
    float4 xs = xp[s];
    x0 = xs.x; x1 = xs.y; x2 = xs.z;
    a0 = lrelu(x0 * us[0] + x1 * us[4] + x2 * us[8]  + ad0);
    a1 = lrelu(x0 * us[1] + x1 * us[5] + x2 * us[9]  + ad1);
    a2 = lrelu(x0 * us[2] + x1 * us[6] + x2 * us[10] + ad2);
    a3 = lrelu(x0 * us[3] + x1 * us[7] + x2 * us[11] + ad3);
  }
  float m0 = a0, m1 = a1, m2 = a2, m3 = a3;
  for (int base = 32; base < deg; base += 32) {   // rare: deg>32
    if (r < deg - base) {
      int s = srclist[off + base + r];
      float4 xs = xp[s];
      m0 = fmaxf(m0, lrelu(xs.x * us[0] + xs.y * us[4] + xs.z * us[8]  + ad0));
      m1 = fmaxf(m1, lrelu(xs.x * us[1] + xs.y * us[5] + xs.z * us[9]  + ad1));
      m2 = fmaxf(m2, lrelu(xs.x * us[2] + xs.y * us[6] + xs.z * us[10] + ad2));
      m3 = fmaxf(m3, lrelu(xs.x * us[3] + xs.y * us[7] + xs.z * us[11] + ad3));
    }
  }
  #pragma unroll
  for (int msk = 16; msk > 0; msk >>= 1) {
    m0 = fmaxf(m0, __shfl_xor(m0, msk, 32)); m1 = fmaxf(m1, __shfl_xor(m1, msk, 32));
    m2 = fmaxf(m2, __shfl_xor(m2, msk, 32)); m3 = fmaxf(m3, __shfl_xor(m3, msk, 32));
  }

  float e0 = (r < c0) ? __expf(a0 - m0) : 0.f;
  float e1 = (r < c0) ? __expf(a1 - m1) : 0.f;
  float e2 = (r < c0) ? __expf(a2 - m2) : 0.f;
  float e3 = (r < c0) ? __expf(a3 - m3) : 0.f;
  float d0 = e0, d1 = e1, d2 = e2, d3 = e3;
  float xa00 = e0 * x0, xa01 = e1 * x0, xa02 = e2 * x0, xa03 = e3 * x0;
  float xa10 = e0 * x1, xa11 = e1 * x1, xa12 = e2 * x1, xa13 = e3 * x1;
  float xa20 = e0 * x2, xa21 = e1 * x2, xa22 = e2 * x2, xa23 = e3 * x2;

  for (int base = 32; base < deg; base += 32) {   // rare
    if (r < deg - base) {
      int s = srclist[off + base + r];
      float4 xs = xp[s];
      float ee0 = __expf(lrelu(xs.x * us[0] + xs.y * us[4] + xs.z * us[8]  + ad0) - m0);
      float ee1 = __expf(lrelu(xs.x * us[1] + xs.y * us[5] + xs.z * us[9]  + ad1) - m1);
      float ee2 = __expf(lrelu(xs.x * us[2] + xs.y * us[6] + xs.z * us[10] + ad2) - m2);
      float ee3 = __expf(lrelu(xs.x * us[3] + xs.y * us[7] + xs.z * us[11] + ad3) - m3);
      d0 += ee0; d1 += ee1; d2 += ee2; d3 += ee3;
      xa00 += ee0 * xs.x; xa01 += ee1 * xs.x; xa02 += ee2 * xs.x; xa03 += ee3 * xs.x;
      xa10 += ee0 * xs.y; xa11 += ee1 * xs.y; xa12 += ee2 * xs.y; xa13 += ee3 * xs.y;
      xa20 += ee0 * xs.z; xa21 += ee1 * xs.z; xa22 += ee2 * xs.z; xa23 += ee3 * xs.z;
    }
  }

  #pragma unroll
  for (int msk = 16; msk > 0; msk >>= 1) {
    d0 += __shfl_xor(d0, msk, 32); d1 += __shfl_xor(d1, msk, 32);
    d2 += __shfl_xor(d2, msk, 32); d3 += __shfl_xor(d3, msk, 32);
    xa00 += __shfl_xor(xa00, msk, 32); xa01 += __shfl_xor(xa01, msk, 32);
    xa02 += __shfl_xor(xa02, msk, 32); xa03 += __shfl_xor(xa03, msk, 32);
    xa10 += __shfl_xor(xa10, msk, 32); xa11 += __shfl_xor(xa11, msk, 32);
    xa12 += __shfl_xor(xa12, msk, 32); xa13 += __shfl_xor(xa13, msk, 32);
    xa20 += __shfl_xor(xa20, msk, 32); xa21 += __shfl_xor(xa21, msk, 32);
    xa22 += __shfl_xor(xa22, msk, 32); xa23 += __shfl_xor(xa23, msk, 32);
  }

  if (r < 16) {
    int j = r;
    float v =
      j == 0 ? d0 : j == 1 ? d1 : j == 2 ? d2 : j == 3 ? d3 :
      j == 4 ? xa00 : j == 5 ? xa01 : j == 6 ? xa02 : j == 7 ? xa03 :
      j == 8 ? xa10 : j == 9 ? xa11 : j == 10 ? xa12 : j == 11 ? xa13 :
      j == 12 ? xa20 : j == 13 ? xa21 : j == 14 ? xa22 : xa23;
    X[(size_t)n * 16 + j] = v;
  }
}

// ---------------- Fused expand + split-bf16 MFMA GEMM + layer-2 scores ----------------
__global__ __launch_bounds__(256) void k_mm2(
    const float* __restrict__ Xc, const float* __restrict__ W1, const float* __restrict__ b1,
    const ushort_t* __restrict__ w2hi, const ushort_t* __restrict__ w2lo,
    const float* __restrict__ att_src2, const float* __restrict__ att_dst2,
    ushort_t* __restrict__ h2, float* __restrict__ a_src2, float* __restrict__ a_dst2, int N)
{
  __shared__ ushort_t h1hi[32 * 256];
  __shared__ ushort_t h1lo[32 * 256];
  __shared__ float Xs[512];
  __shared__ float W1s[768];
  __shared__ float b1s[256];
  __shared__ float invs[128];
  __shared__ float sred_s[32][4];
  __shared__ float sred_d[32][4];

  int t = threadIdx.x;
  int n0 = blockIdx.x * 32;

  for (int i = t; i < 768; i += 256) W1s[i] = W1[i];
  b1s[t] = b1[t];
  for (int i = t; i < 512; i += 256) {
    int idx = n0 * 16 + i;
    Xs[i] = (idx < N * 16) ? Xc[idx] : 0.f;
  }
  __syncthreads();
  if (t < 128) invs[t] = 1.f / (Xs[(t >> 2) * 16 + (t & 3)] + 1e-16f);
  __syncthreads();

  {
    int c = t, h = t >> 6;
    float w0 = W1s[c], w1 = W1s[256 + c], w2v = W1s[512 + c], bb = b1s[c];
    #pragma unroll 4
    for (int i = 0; i < 32; ++i) {
      float inv = invs[i * 4 + h];
      float X0 = Xs[i * 16 + 4 + h] * inv;
      float X1 = Xs[i * 16 + 8 + h] * inv;
      float X2 = Xs[i * 16 + 12 + h] * inv;
      float v = fmaf(w0, X0, fmaf(w1, X1, fmaf(w2v, X2, bb)));
      v = v > 0.f ? v : __expf(v) - 1.f;      // ELU
      ushort_t hi = bf16_rn(v);
      ushort_t lo = bf16_rn(v - bf16_to_f(hi));
      int idx = (i * 256 + c) ^ ((i & 7) << 3);   // T2 XOR swizzle (ushort units)
      h1hi[idx] = hi;
      h1lo[idx] = lo;
    }
  }
  __syncthreads();

  int lane = t & 63;
  int w = t >> 6;
  int lm = lane & 15, lg = lane >> 4;

  f32x4 acc[2][2];
  f32x4 zz = {0.f, 0.f, 0.f, 0.f};
  acc[0][0] = zz; acc[0][1] = zz; acc[1][0] = zz; acc[1][1] = zz;

  int rowA0 = lm, rowA1 = 16 + lm;
  int swz0 = (rowA0 & 7) << 3, swz1 = (rowA1 & 7) << 3;

  for (int kc = 0; kc < 8; ++kc) {
    int ks = kc * 32 + lg * 8;
    int ia0 = (rowA0 * 256 + ks) ^ swz0;
    int ia1 = (rowA1 * 256 + ks) ^ swz1;
    bf16x8 ah0 = *(const bf16x8*)&h1hi[ia0];
    bf16x8 al0 = *(const bf16x8*)&h1lo[ia0];
    bf16x8 ah1 = *(const bf16x8*)&h1hi[ia1];
    bf16x8 al1 = *(const bf16x8*)&h1lo[ia1];
    size_t bb0 = ((size_t)((kc * 4 + lg) * 128) + (w * 32 + lm)) * 8;
    size_t bb1 = bb0 + 16 * 8;
    bf16x8 bh0 = *(const bf16x8*)&w2hi[bb0];
    bf16x8 bl0 = *(const bf16x8*)&w2lo[bb0];
    bf16x8 bh1 = *(const bf16x8*)&w2hi[bb1];
    bf16x8 bl1 = *(const bf16x8*)&w2lo[bb1];

    acc[0][0] = __builtin_amdgcn_mfma_f32_16x16x32_bf16(ah0, bh0, acc[0][0], 0, 0, 0);
    acc[0][1] = __builtin_amdgcn_mfma_f32_16x16x32_bf16(ah0, bh1, acc[0][1], 0, 0, 0);
    acc[1][0] = __builtin_amdgcn_mfma_f32_16x16x32_bf16(ah1, bh0, acc[1][0], 0, 0, 0);
    acc[1][1] = __builtin_amdgcn_mfma_f32_16x16x32_bf16(ah1, bh1, acc[1][1], 0, 0, 0);
    acc[0][0] = __builtin_amdgcn_mfma_f32_16x16x32_bf16(ah0, bl0, acc[0][0], 0, 0, 0);
    acc[0][1] = __builtin_amdgcn_mfma_f32_16x16x32_bf16(ah0, bl1, acc[0][1], 0, 0, 0);
    acc[1][0] = __builtin_amdgcn_mfma_f32_16x16x32_bf16(ah1, bl0, acc[1][0], 0, 0, 0);
    acc[1][1] = __builtin_amdgcn_mfma_f32_16x16x32_bf16(ah1, bl1, acc[1][1], 0, 0, 0);
    acc[0][0] = __builtin_amdgcn_mfma_f32_16x16x32_bf16(al0, bh0, acc[0][0], 0, 0, 0);
    acc[0][1] = __builtin_amdgcn_mfma_f32_16x16x32_bf16(al0, bh1, acc[0][1], 0, 0, 0);
    acc[1][0] = __builtin_amdgcn_mfma_f32_16x16x32_bf16(al1, bh0, acc[1][0], 0, 0, 0);
    acc[1][1] = __builtin_amdgcn_mfma_f32_16x16x32_bf16(al1, bh1, acc[1][1], 0, 0, 0);
  }

  // epilogue: C layout col=lane&15, row=(lane>>4)*4+reg  [verified m89/m91]
  float as0 = att_src2[w * 32 + lm], as1 = att_src2[w * 32 + 16 + lm];
  float ad0 = att_dst2[w * 32 + lm], ad1 = att_dst2[w * 32 + 16 + lm];
  #pragma unroll
  for (int mi = 0; mi < 2; ++mi) {
    float ps[4], pd[4];
    #pragma unroll
    for (int rg = 0; rg < 4; ++rg) {
      float c0v = acc[mi][0][rg], c1v = acc[mi][1][rg];
      int nrow = n0 + mi * 16 + lg * 4 + rg;
      if (nrow < N) {
        h2[(size_t)nrow * 128 + w * 32 + lm] = bf16_rn(c0v);
        h2[(size_t)nrow * 128 + w * 32 + 16 + lm] = bf16_rn(c1v);
      }
      ps[rg] = c0v * as0 + c1v * as1;
      pd[rg] = c0v * ad0 + c1v * ad1;
    }
    #pragma unroll
    for (int rg = 0; rg < 4; ++rg) {
      #pragma unroll
      for (int m = 8; m >= 1; m >>= 1) {
        ps[rg] += __shfl_xor(ps[rg], m, 64);
        pd[rg] += __shfl_xor(pd[rg], m, 64);
      }
      if (lm == 0) {
        int row = mi * 16 + lg * 4 + rg;
        sred_s[row][w] = ps[rg];
        sred_d[row][w] = pd[rg];
      }
    }
  }
  __syncthreads();
  if (t < 32) {
    int n = n0 + t;
    if (n < N) {
      a_src2[n] = sred_s[t][0] + sred_s[t][1] + sred_s[t][2] + sred_s[t][3];
      a_dst2[n] = sred_d[t][0] + sred_d[t][1] + sred_d[t][2] + sred_d[t][3];
    }
  }
}

// ---------------- Layer-2 aggregate -> out [N,128] ----------------
__global__ __launch_bounds__(256) void k_agg2(
    const ushort_t* __restrict__ h2, const float* __restrict__ b2,
    const float* __restrict__ a_src2, const float* __restrict__ a_dst2,
    const int* __restrict__ offsets, const int* __restrict__ srclist,
    float* __restrict__ out, int N)
{
  int t = threadIdx.x, lane = t & 63;
  int g = lane >> 5, r = lane & 31;
  int n = blockIdx.x * 8 + (t >> 6) * 2 + g;
  if (n >= N) return;
  int off = offsets[n], deg = offsets[n + 1] - off;
  float adn = a_dst2[n];

  int c0 = min(deg, 32);
  int s_l = 0; float a_l = -1e30f;
  if (r < c0) { s_l = srclist[off + r]; a_l = lrelu(a_src2[s_l] + adn); }
  float m = a_l;
  for (int base = 32; base < deg; base += 32)    // rare
    if (r < deg - base) m = fmaxf(m, lrelu(a_src2[srclist[off + base + r]] + adn));
  #pragma unroll
  for (int msk = 16; msk > 0; msk >>= 1) m = fmaxf(m, __shfl_xor(m, msk, 32));

  float e_l = (r < c0) ? __expf(a_l - m) : 0.f;
  float den_p = e_l;
  float4 acc = {0.f, 0.f, 0.f, 0.f};

  int j = 0;
  for (; j + 4 <= c0; j += 4) {
    int   sA = __shfl(s_l, j, 32),     sB = __shfl(s_l, j + 1, 32);
    int   sC = __shfl(s_l, j + 2, 32), sD = __shfl(s_l, j + 3, 32);
    float eA = __shfl(e_l, j, 32),     eB = __shfl(e_l, j + 1, 32);
    float eC = __shfl(e_l, j + 2, 32), eD = __shfl(e_l, j + 3, 32);
    float4 hA = ld_h2q(h2, sA, r);
    float4 hB = ld_h2q(h2, sB, r);
    float4 hC = ld_h2q(h2, sC, r);
    float4 hD = ld_h2q(h2, sD, r);
    acc.x += eA * hA.x + eB * hB.x + eC * hC.x + eD * hD.x;
    acc.y += eA * hA.y + eB * hB.y + eC * hC.y + eD * hD.y;
    acc.z += eA * hA.z + eB * hB.z + eC * hC.z + eD * hD.z;
    acc.w += eA * hA.w + eB * hB.w + eC * hC.w + eD * hD.w;
  }
  for (; j < c0; ++j) {
    int sA = __shfl(s_l, j, 32);
    float eA = __shfl(e_l, j, 32);
    float4 hA = ld_h2q(h2, sA, r);
    acc.x += eA * hA.x; acc.y += eA * hA.y; acc.z += eA * hA.z; acc.w += eA * hA.w;
  }
  for (int base = 32; base < deg; base += 32) {  // rare
    int rem = min(32, deg - base);
    int sl2 = 0; float el2 = 0.f;
    if (r < rem) { sl2 = srclist[off + base + r]; el2 = __expf(lrelu(a_src2[sl2] + adn) - m); }
    den_p += el2;
    for (int q = 0; q < rem; ++q) {
      int s = __shfl(sl2, q, 32);
      float e = __shfl(el2, q, 32);
      float4 hv = ld_h2q(h2, s, r);
      acc.x += e * hv.x; acc.y += e * hv.y; acc.z += e * hv.z; acc.w += e * hv.w;
    }
  }
  #pragma unroll
  for (int msk = 16; msk > 0; msk >>= 1) den_p += __shfl_xor(den_p, msk, 32);
  float inv = 1.f / (den_p + 1e-16f);
  float4 bb = *(const float4*)&b2[r * 4];
  float4 o = {acc.x * inv + bb.x, acc.y * inv + bb.y, acc.z * inv + bb.z, acc.w * inv + bb.w};
  *(float4*)&out[(size_t)n * 128 + r * 4] = o;
}

extern "C" void kernel_launch(void* const* d_in, const int* in_sizes, int n_in,
                              void* d_out, int out_size, void* d_ws, size_t ws_size,
                              hipStream_t stream)
{
  const float* x        = (const float*)d_in[0];
  const int*   ei       = (const int*)d_in[1];
  const float* W1       = (const float*)d_in[2];
  const float* att_src1 = (const float*)d_in[3];
  const float* att_dst1 = (const float*)d_in[4];
  const float* b1       = (const float*)d_in[5];
  const float* W2       = (const float*)d_in[6];
  const float* att_src2 = (const float*)d_in[7];
  const float* att_dst2 = (const float*)d_in[8];
  const float* b2       = (const float*)d_in[9];
  float* out = (float*)d_out;

  int N = in_sizes[0] / 3;
  int E = in_sizes[1] / 2;
  int NB = (N + 127) >> 7;     // 128 nodes per bucket; NB <= 512 for N <= 65536
  int NPX = (N + 255) / 256;
  int nEB = (E + 2047) / 2048;

  char* p = (char*)d_ws;
  auto alloc = [&](size_t bytes) -> char* {
    char* r = p;
    p += (bytes + 255) & ~(size_t)255;
    return r;
  };
  float*    uv      = (float*)alloc(24 * 4);
  ushort_t* w2hi    = (ushort_t*)alloc(32768 * 2);
  ushort_t* w2lo    = (ushort_t*)alloc(32768 * 2);
  float4*   xp      = (float4*)alloc((size_t)N * 16);
  float*    a_src2  = (float*)alloc((size_t)N * 4);
  float*    a_dst2  = (float*)alloc((size_t)N * 4);
  int*      hist    = (int*)alloc(512 * 4);
  int*      cbase   = (int*)alloc(513 * 4);
  int*      cursorB = (int*)alloc(512 * 4);
  unsigned* pairs   = (unsigned*)alloc((size_t)E * 4);
  int*      offsets = (int*)alloc((size_t)(N + 1) * 4);
  int*      srclist = (int*)alloc((size_t)(E + N) * 4);
  float*    Xc      = (float*)alloc((size_t)16 * N * 4);
  ushort_t* h2      = (ushort_t*)alloc((size_t)128 * N * 2);

  hipMemsetAsync(hist, 0, 512 * 4, stream);
  k_prep<<<17 + NPX + nEB, 256, 0, stream>>>(W1, att_src1, att_dst1, W2, x, ei, E, NB, NPX,
                                             w2hi, w2lo, uv, xp, hist, N);
  k_scanB<<<1, 512, 0, stream>>>(hist, NB, E, cbase, cursorB);
  k_scatter<<<nEB, 256, 0, stream>>>(ei, E, NB, cursorB, pairs);
  k_bucket<<<NB, 256, 0, stream>>>(pairs, cbase, N, NB, E, offsets, srclist);
  k_agg1<<<(N + 7) / 8, 256, 0, stream>>>(xp, uv, offsets, srclist, Xc, N);
  k_mm2<<<(N + 31) / 32, 256, 0, stream>>>(Xc, W1, b1, w2hi, w2lo, att_src2, att_dst2, h2, a_src2, a_dst2, N);
  k_agg2<<<(N + 7) / 8, 256, 0, stream>>>(h2, b2, a_src2, a_dst2, offsets, srclist, out, N);
}